// Round 1
// baseline (1016.753 us; speedup 1.0000x reference)
//
#include <hip/hip_runtime.h>

// ---------------- CSR build ----------------

__global__ __launch_bounds__(256) void k_hist(const int* __restrict__ col, int* __restrict__ cnt, int e) {
    int i = blockIdx.x * 256 + threadIdx.x;
    if (i < e) atomicAdd(&cnt[col[i]], 1);
}

__global__ __launch_bounds__(256) void k_dinv(const int* __restrict__ cnt, float* __restrict__ dinv, int n) {
    int i = blockIdx.x * 256 + threadIdx.x;
    if (i < n) dinv[i] = rsqrtf((float)(cnt[i] + 1));  // +1 self loop
}

// block-level inclusive scan of 1024 elements (256 thr x 4)
__global__ __launch_bounds__(256) void k_scan1(const int* __restrict__ cnt, int* __restrict__ colptr,
                                               int* __restrict__ bsum, int n) {
    __shared__ int lds[256];
    int t = threadIdx.x;
    int base = blockIdx.x * 1024;
    int idx = base + t * 4;
    int4 v = make_int4(0, 0, 0, 0);
    if (idx + 3 < n) {
        v = *(const int4*)(cnt + idx);
    } else {
        if (idx     < n) v.x = cnt[idx];
        if (idx + 1 < n) v.y = cnt[idx + 1];
        if (idx + 2 < n) v.z = cnt[idx + 2];
        if (idx + 3 < n) v.w = cnt[idx + 3];
    }
    int s1 = v.x, s2 = s1 + v.y, s3 = s2 + v.z, s4 = s3 + v.w;
    lds[t] = s4;
    __syncthreads();
    for (int off = 1; off < 256; off <<= 1) {
        int mine = lds[t];
        int add  = (t >= off) ? lds[t - off] : 0;
        __syncthreads();
        lds[t] = mine + add;
        __syncthreads();
    }
    int incl = lds[t];
    int excl = incl - s4;
    if (t == 255) bsum[blockIdx.x] = incl;
    if (idx     < n) colptr[idx + 1] = excl + s1;
    if (idx + 1 < n) colptr[idx + 2] = excl + s2;
    if (idx + 2 < n) colptr[idx + 3] = excl + s3;
    if (idx + 3 < n) colptr[idx + 4] = excl + s4;
}

__global__ __launch_bounds__(128) void k_scan2(const int* __restrict__ bsum, int* __restrict__ boff, int nb) {
    __shared__ int lds[128];
    int t = threadIdx.x;
    int v = (t < nb) ? bsum[t] : 0;
    lds[t] = v;
    __syncthreads();
    for (int off = 1; off < 128; off <<= 1) {
        int mine = lds[t];
        int add  = (t >= off) ? lds[t - off] : 0;
        __syncthreads();
        lds[t] = mine + add;
        __syncthreads();
    }
    if (t < nb) boff[t] = lds[t] - v;  // exclusive
}

__global__ __launch_bounds__(256) void k_scan3(int* __restrict__ colptr, const int* __restrict__ boff,
                                               int* __restrict__ cursor, int n) {
    int j = blockIdx.x * 256 + threadIdx.x;
    if (j > n) return;
    int val;
    if (j == 0) {
        val = 0;
        colptr[0] = 0;
    } else {
        val = colptr[j] + boff[(j - 1) >> 10];
        colptr[j] = val;
    }
    if (j < n) cursor[j] = val;
}

__global__ __launch_bounds__(256) void k_fill(const int* __restrict__ row, const int* __restrict__ col,
                                              int* __restrict__ cursor, int* __restrict__ esrc, int e) {
    int i = blockIdx.x * 256 + threadIdx.x;
    if (i < e) {
        int c = col[i];
        int pos = atomicAdd(&cursor[c], 1);
        esrc[pos] = row[i];
    }
}

// ---------------- GEMM: out[r] = dinv[r] * (in[r] @ W + b) ----------------
// 64 rows x 128 cols per block; 256 threads; 4x8 accumulators per thread.
// W staged in LDS with a +4*(c/32) offset swizzle (2-way max bank aliasing);
// in-tile staged row-major with stride 129 (2-way max).
__global__ __launch_bounds__(256) void k_gemm(const float* __restrict__ in, const float* __restrict__ w,
                                              const float* __restrict__ bias, const float* __restrict__ dinv,
                                              float* __restrict__ out, int n) {
    __shared__ float ws[128 * 144];
    __shared__ float ins[64 * 129];
    int t = threadIdx.x;

    // stage W (128x128) swizzled: word W(c) = c + 4*(c>>5)
    #pragma unroll
    for (int i = 0; i < 16; i++) {
        int fi = t + i * 256;           // float4 index 0..4095
        int k  = fi >> 5;
        int c0 = (fi & 31) * 4;
        float4 v = ((const float4*)w)[fi];
        int W = c0 + ((c0 >> 5) << 2);
        *((float4*)&ws[k * 144 + W]) = v;
    }
    // stage in-tile (64 rows x 128), row-major stride 129
    int rbase = blockIdx.x * 64;
    #pragma unroll
    for (int i = 0; i < 8; i++) {
        int fi = t + i * 256;           // 0..2047
        int rl = fi >> 5;
        int q  = fi & 31;
        int r  = rbase + rl;
        float4 v = make_float4(0.f, 0.f, 0.f, 0.f);
        if (r < n) v = ((const float4*)in)[r * 32 + q];
        float* p = &ins[rl * 129 + q * 4];
        p[0] = v.x; p[1] = v.y; p[2] = v.z; p[3] = v.w;
    }
    __syncthreads();

    int cg = t & 15, rg = t >> 4;
    int c0 = cg * 8;
    int W0 = c0 + ((c0 >> 5) << 2);

    float acc[4][8];
    #pragma unroll
    for (int i = 0; i < 4; i++)
        #pragma unroll
        for (int j = 0; j < 8; j++) acc[i][j] = 0.f;

    #pragma unroll 8
    for (int k = 0; k < 128; k++) {
        float4 w0 = *((const float4*)&ws[k * 144 + W0]);
        float4 w1 = *((const float4*)&ws[k * 144 + W0 + 4]);
        float wv[8] = {w0.x, w0.y, w0.z, w0.w, w1.x, w1.y, w1.z, w1.w};
        float av[4];
        av[0] = ins[(rg * 4 + 0) * 129 + k];
        av[1] = ins[(rg * 4 + 1) * 129 + k];
        av[2] = ins[(rg * 4 + 2) * 129 + k];
        av[3] = ins[(rg * 4 + 3) * 129 + k];
        #pragma unroll
        for (int i = 0; i < 4; i++)
            #pragma unroll
            for (int j = 0; j < 8; j++) acc[i][j] = fmaf(av[i], wv[j], acc[i][j]);
    }

    float bl[8];
    #pragma unroll
    for (int j = 0; j < 8; j++) bl[j] = bias[c0 + j];
    #pragma unroll
    for (int i = 0; i < 4; i++) {
        int r = rbase + rg * 4 + i;
        if (r >= n) break;
        float dv = dinv[r];
        float4 o0, o1;
        o0.x = dv * (acc[i][0] + bl[0]); o0.y = dv * (acc[i][1] + bl[1]);
        o0.z = dv * (acc[i][2] + bl[2]); o0.w = dv * (acc[i][3] + bl[3]);
        o1.x = dv * (acc[i][4] + bl[4]); o1.y = dv * (acc[i][5] + bl[5]);
        o1.z = dv * (acc[i][6] + bl[6]); o1.w = dv * (acc[i][7] + bl[7]);
        ((float4*)out)[r * 32 + cg * 2]     = o0;
        ((float4*)out)[r * 32 + cg * 2 + 1] = o1;
    }
}

// ---------------- Aggregation: B[v] = relu(dinv[v] * (A[v] + sum_{src} A[src])) ----------------
__global__ __launch_bounds__(128) void k_agg(const float* __restrict__ A, const int* __restrict__ colptr,
                                             const int* __restrict__ esrc, const float* __restrict__ dinv,
                                             float* __restrict__ B) {
    int v = blockIdx.x;
    int c = threadIdx.x;
    int p0 = colptr[v], p1 = colptr[v + 1];
    float acc = A[v * 128 + c];  // self loop (already dinv[v]-scaled row)
    for (int p = p0; p < p1; p++) {
        int s = esrc[p];
        acc += A[s * 128 + c];
    }
    float val = dinv[v] * acc;
    B[v * 128 + c] = fmaxf(val, 0.f);
}

// ---------------- Pooling (batch is sorted) ----------------
__global__ __launch_bounds__(128) void k_pool(const float* __restrict__ B, const int* __restrict__ batch,
                                              float* __restrict__ gsum, int* __restrict__ gcnt, int n) {
    int c = threadIdx.x;
    int base = blockIdx.x * 64;
    if (base >= n) return;
    int end = min(base + 64, n);
    int curg = batch[base];
    float acc = 0.f;
    int cnt = 0;
    for (int i = base; i < end; i++) {
        int g = batch[i];
        if (g != curg) {
            atomicAdd(&gsum[curg * 128 + c], acc);
            if (c == 0) atomicAdd(&gcnt[curg], cnt);
            acc = 0.f; cnt = 0; curg = g;
        }
        acc += B[i * 128 + c];
        cnt++;
    }
    atomicAdd(&gsum[curg * 128 + c], acc);
    if (c == 0) atomicAdd(&gcnt[curg], cnt);
}

// ---------------- Head: out[g] = relu(mean_g @ hw1 + hb1) @ hw2 + hb2 ----------------
__global__ __launch_bounds__(128) void k_head(const float* __restrict__ gsum, const int* __restrict__ gcnt,
                                              const float* __restrict__ hw1, const float* __restrict__ hb1,
                                              const float* __restrict__ hw2, const float* __restrict__ hb2,
                                              float* __restrict__ out) {
    __shared__ float mean[128];
    __shared__ float red[128];
    int g = blockIdx.x;
    int c = threadIdx.x;
    float cntf = fmaxf((float)gcnt[g], 1.0f);
    mean[c] = gsum[g * 128 + c] / cntf;
    __syncthreads();
    float h = hb1[c];
    for (int k = 0; k < 128; k++) h = fmaf(mean[k], hw1[k * 128 + c], h);
    h = fmaxf(h, 0.f);
    red[c] = h * hw2[c];
    __syncthreads();
    for (int s = 64; s > 0; s >>= 1) {
        if (c < s) red[c] += red[c + s];
        __syncthreads();
    }
    if (c == 0) out[g] = red[0] + hb2[0];
}

// ---------------- launch ----------------
extern "C" void kernel_launch(void* const* d_in, const int* in_sizes, int n_in,
                              void* d_out, int out_size, void* d_ws, size_t ws_size,
                              hipStream_t stream) {
    const float* x   = (const float*)d_in[0];
    const int*  edge = (const int*)d_in[1];
    const int*  batch= (const int*)d_in[2];
    const float* w1  = (const float*)d_in[3];
    const float* b1  = (const float*)d_in[4];
    const float* w2  = (const float*)d_in[5];
    const float* b2  = (const float*)d_in[6];
    const float* w3  = (const float*)d_in[7];
    const float* b3  = (const float*)d_in[8];
    const float* hw1 = (const float*)d_in[9];
    const float* hb1 = (const float*)d_in[10];
    const float* hw2 = (const float*)d_in[11];
    const float* hb2 = (const float*)d_in[12];
    float* out = (float*)d_out;

    const int n = in_sizes[0] / 128;
    const int e = in_sizes[1] / 2;
    const int* row = edge;
    const int* col = edge + e;

    char* wsb = (char*)d_ws;
    size_t off = 0;
    auto alloc = [&](size_t bytes) -> void* {
        void* p = wsb + off;
        off = (off + bytes + 511) & ~size_t(511);
        return p;
    };
    float* A      = (float*)alloc((size_t)n * 128 * 4);
    float* Bb     = (float*)alloc((size_t)n * 128 * 4);
    float* dinv   = (float*)alloc((size_t)n * 4);
    int*   cnt    = (int*)  alloc((size_t)n * 4);
    int*   colptr = (int*)  alloc((size_t)(n + 1) * 4);
    int*   cursor = (int*)  alloc((size_t)n * 4);
    int*   bsum   = (int*)  alloc(512);
    int*   boff   = (int*)  alloc(512);
    int*   esrc   = (int*)  alloc((size_t)e * 4);
    float* gsum   = (float*)alloc(64 * 128 * 4);
    int*   gcnt   = (int*)  alloc(64 * 4);

    hipMemsetAsync(cnt,  0, (size_t)n * 4, stream);
    hipMemsetAsync(gsum, 0, 64 * 128 * 4, stream);
    hipMemsetAsync(gcnt, 0, 64 * 4, stream);

    k_hist<<<(e + 255) / 256, 256, 0, stream>>>(col, cnt, e);
    k_dinv<<<(n + 255) / 256, 256, 0, stream>>>(cnt, dinv, n);
    int nb = (n + 1023) / 1024;
    k_scan1<<<nb, 256, 0, stream>>>(cnt, colptr, bsum, n);
    k_scan2<<<1, 128, 0, stream>>>(bsum, boff, nb);
    k_scan3<<<(n + 1 + 255) / 256, 256, 0, stream>>>(colptr, boff, cursor, n);
    k_fill<<<(e + 255) / 256, 256, 0, stream>>>(row, col, cursor, esrc, e);

    int gb = (n + 63) / 64;
    k_gemm<<<gb, 256, 0, stream>>>(x,  w1, b1, dinv, A, n);
    k_agg <<<n, 128, 0, stream>>>(A, colptr, esrc, dinv, Bb);
    k_gemm<<<gb, 256, 0, stream>>>(Bb, w2, b2, dinv, A, n);
    k_agg <<<n, 128, 0, stream>>>(A, colptr, esrc, dinv, Bb);
    k_gemm<<<gb, 256, 0, stream>>>(Bb, w3, b3, dinv, A, n);
    k_agg <<<n, 128, 0, stream>>>(A, colptr, esrc, dinv, Bb);

    k_pool<<<(n + 63) / 64, 128, 0, stream>>>(Bb, batch, gsum, gcnt, n);
    k_head<<<64, 128, 0, stream>>>(gsum, gcnt, hw1, hb1, hw2, hb2, out);
}

// Round 3
// 815.113 us; speedup vs baseline: 1.2474x; 1.2474x over previous
//
#include <hip/hip_runtime.h>

// ---------------- CSR build ----------------

__global__ __launch_bounds__(256) void k_hist(const int* __restrict__ col, int* __restrict__ cnt, int e) {
    int i = blockIdx.x * 256 + threadIdx.x;
    if (i < e) atomicAdd(&cnt[col[i]], 1);
}

__global__ __launch_bounds__(256) void k_dinv(const int* __restrict__ cnt, float* __restrict__ dinv, int n) {
    int i = blockIdx.x * 256 + threadIdx.x;
    if (i < n) dinv[i] = rsqrtf((float)(cnt[i] + 1));  // +1 self loop
}

// block-level inclusive scan of 1024 elements (256 thr x 4)
__global__ __launch_bounds__(256) void k_scan1(const int* __restrict__ cnt, int* __restrict__ colptr,
                                               int* __restrict__ bsum, int n) {
    __shared__ int lds[256];
    int t = threadIdx.x;
    int base = blockIdx.x * 1024;
    int idx = base + t * 4;
    int4 v = make_int4(0, 0, 0, 0);
    if (idx + 3 < n) {
        v = *(const int4*)(cnt + idx);
    } else {
        if (idx     < n) v.x = cnt[idx];
        if (idx + 1 < n) v.y = cnt[idx + 1];
        if (idx + 2 < n) v.z = cnt[idx + 2];
        if (idx + 3 < n) v.w = cnt[idx + 3];
    }
    int s1 = v.x, s2 = s1 + v.y, s3 = s2 + v.z, s4 = s3 + v.w;
    lds[t] = s4;
    __syncthreads();
    for (int off = 1; off < 256; off <<= 1) {
        int mine = lds[t];
        int add  = (t >= off) ? lds[t - off] : 0;
        __syncthreads();
        lds[t] = mine + add;
        __syncthreads();
    }
    int incl = lds[t];
    int excl = incl - s4;
    if (t == 255) bsum[blockIdx.x] = incl;
    if (idx     < n) colptr[idx + 1] = excl + s1;
    if (idx + 1 < n) colptr[idx + 2] = excl + s2;
    if (idx + 2 < n) colptr[idx + 3] = excl + s3;
    if (idx + 3 < n) colptr[idx + 4] = excl + s4;
}

__global__ __launch_bounds__(128) void k_scan2(const int* __restrict__ bsum, int* __restrict__ boff, int nb) {
    __shared__ int lds[128];
    int t = threadIdx.x;
    int v = (t < nb) ? bsum[t] : 0;
    lds[t] = v;
    __syncthreads();
    for (int off = 1; off < 128; off <<= 1) {
        int mine = lds[t];
        int add  = (t >= off) ? lds[t - off] : 0;
        __syncthreads();
        lds[t] = mine + add;
        __syncthreads();
    }
    if (t < nb) boff[t] = lds[t] - v;  // exclusive
}

__global__ __launch_bounds__(256) void k_scan3(int* __restrict__ colptr, const int* __restrict__ boff,
                                               int* __restrict__ cursor, int n) {
    int j = blockIdx.x * 256 + threadIdx.x;
    if (j > n) return;
    int val;
    if (j == 0) {
        val = 0;
        colptr[0] = 0;
    } else {
        val = colptr[j] + boff[(j - 1) >> 10];
        colptr[j] = val;
    }
    if (j < n) cursor[j] = val;
}

__global__ __launch_bounds__(256) void k_fill(const int* __restrict__ row, const int* __restrict__ col,
                                              int* __restrict__ cursor, int* __restrict__ esrc, int e) {
    int i = blockIdx.x * 256 + threadIdx.x;
    if (i < e) {
        int c = col[i];
        int pos = atomicAdd(&cursor[c], 1);
        esrc[pos] = row[i];
    }
}

// ---------------- GEMM: out[r] = dinv[r] * (in[r] @ W + b) ----------------
// 128 rows x 128 cols per block; 512 threads (8 waves = 2/SIMD); 4x8 acc/thread.
// ws stride 144 (additive swizzle range [0,140) fits); ins stride 129.
__global__ __launch_bounds__(512) void k_gemm(const float* __restrict__ in, const float* __restrict__ w,
                                              const float* __restrict__ bias, const float* __restrict__ dinv,
                                              float* __restrict__ out, int n) {
    __shared__ float ws[128 * 144];
    __shared__ float ins[128 * 129];
    int t = threadIdx.x;

    // stage W (128x128): word W(c) = c + 4*(c>>5) within row, row stride 144
    #pragma unroll
    for (int i = 0; i < 8; i++) {
        int fi = t + i * 512;           // float4 index 0..4095
        int k  = fi >> 5;
        int c0 = (fi & 31) * 4;
        float4 v = ((const float4*)w)[fi];
        int W = c0 + ((c0 >> 5) << 2);
        *((float4*)&ws[k * 144 + W]) = v;
    }
    // stage in-tile (128 rows x 128), row-major stride 129
    int rbase = blockIdx.x * 128;
    #pragma unroll
    for (int i = 0; i < 8; i++) {
        int fi = t + i * 512;           // 0..4095
        int rl = fi >> 5;
        int q  = fi & 31;
        int r  = rbase + rl;
        float4 v = make_float4(0.f, 0.f, 0.f, 0.f);
        if (r < n) v = ((const float4*)in)[r * 32 + q];
        float* p = &ins[rl * 129 + q * 4];
        p[0] = v.x; p[1] = v.y; p[2] = v.z; p[3] = v.w;
    }
    __syncthreads();

    int cg = t & 15, rg = t >> 4;       // cg 0..15, rg 0..31
    int c0 = cg * 8;
    int W0 = c0 + ((c0 >> 5) << 2);     // max 132, +7 = 139 < 144 OK

    float acc[4][8];
    #pragma unroll
    for (int i = 0; i < 4; i++)
        #pragma unroll
        for (int j = 0; j < 8; j++) acc[i][j] = 0.f;

    #pragma unroll 8
    for (int k = 0; k < 128; k++) {
        float4 w0 = *((const float4*)&ws[k * 144 + W0]);
        float4 w1 = *((const float4*)&ws[k * 144 + W0 + 4]);
        float wv[8] = {w0.x, w0.y, w0.z, w0.w, w1.x, w1.y, w1.z, w1.w};
        float av[4];
        av[0] = ins[(rg * 4 + 0) * 129 + k];
        av[1] = ins[(rg * 4 + 1) * 129 + k];
        av[2] = ins[(rg * 4 + 2) * 129 + k];
        av[3] = ins[(rg * 4 + 3) * 129 + k];
        #pragma unroll
        for (int i = 0; i < 4; i++)
            #pragma unroll
            for (int j = 0; j < 8; j++) acc[i][j] = fmaf(av[i], wv[j], acc[i][j]);
    }

    float bl[8];
    #pragma unroll
    for (int j = 0; j < 8; j++) bl[j] = bias[c0 + j];
    #pragma unroll
    for (int i = 0; i < 4; i++) {
        int r = rbase + rg * 4 + i;
        if (r >= n) break;
        float dv = dinv[r];
        float4 o0, o1;
        o0.x = dv * (acc[i][0] + bl[0]); o0.y = dv * (acc[i][1] + bl[1]);
        o0.z = dv * (acc[i][2] + bl[2]); o0.w = dv * (acc[i][3] + bl[3]);
        o1.x = dv * (acc[i][4] + bl[4]); o1.y = dv * (acc[i][5] + bl[5]);
        o1.z = dv * (acc[i][6] + bl[6]); o1.w = dv * (acc[i][7] + bl[7]);
        ((float4*)out)[r * 32 + cg * 2]     = o0;
        ((float4*)out)[r * 32 + cg * 2 + 1] = o1;
    }
}

// ---------------- Aggregation: B[v] = relu(dinv[v] * (A[v] + sum_{src} A[src])) ----------------
// One wave per node, float2 per lane. 4-wide LOAD prefetch (independent loads in
// flight), but a SINGLE accumulator added in strict sequential CSR order — the
// association order matches the bit-exact round-1 kernel.
__global__ __launch_bounds__(256) void k_agg(const float* __restrict__ A, const int* __restrict__ colptr,
                                             const int* __restrict__ esrc, const float* __restrict__ dinv,
                                             float* __restrict__ B, int n) {
    int lane = threadIdx.x & 63;
    int v = blockIdx.x * 4 + (threadIdx.x >> 6);
    if (v >= n) return;
    const float2* __restrict__ A2 = (const float2*)A;
    int p0 = colptr[v], p1 = colptr[v + 1];
    float2 acc = A2[(size_t)v * 64 + lane];  // self loop (row already dinv[v]-scaled)
    int p = p0;
    for (; p + 4 <= p1; p += 4) {
        int s0 = esrc[p];
        int s1 = esrc[p + 1];
        int s2 = esrc[p + 2];
        int s3 = esrc[p + 3];
        float2 v0 = A2[(size_t)s0 * 64 + lane];
        float2 v1 = A2[(size_t)s1 * 64 + lane];
        float2 v2 = A2[(size_t)s2 * 64 + lane];
        float2 v3 = A2[(size_t)s3 * 64 + lane];
        acc.x += v0.x; acc.y += v0.y;
        acc.x += v1.x; acc.y += v1.y;
        acc.x += v2.x; acc.y += v2.y;
        acc.x += v3.x; acc.y += v3.y;
    }
    for (; p < p1; ++p) {
        int s = esrc[p];
        float2 vv = A2[(size_t)s * 64 + lane];
        acc.x += vv.x; acc.y += vv.y;
    }
    float d = dinv[v];
    float ox = fmaxf(d * acc.x, 0.f);
    float oy = fmaxf(d * acc.y, 0.f);
    ((float2*)B)[(size_t)v * 64 + lane] = make_float2(ox, oy);
}

// ---------------- Pooling (batch is sorted) ----------------
__global__ __launch_bounds__(128) void k_pool(const float* __restrict__ B, const int* __restrict__ batch,
                                              float* __restrict__ gsum, int* __restrict__ gcnt, int n) {
    int c = threadIdx.x;
    int base = blockIdx.x * 64;
    if (base >= n) return;
    int end = min(base + 64, n);
    int curg = batch[base];
    float acc = 0.f;
    int cnt = 0;
    for (int i = base; i < end; i++) {
        int g = batch[i];
        if (g != curg) {
            atomicAdd(&gsum[curg * 128 + c], acc);
            if (c == 0) atomicAdd(&gcnt[curg], cnt);
            acc = 0.f; cnt = 0; curg = g;
        }
        acc += B[i * 128 + c];
        cnt++;
    }
    atomicAdd(&gsum[curg * 128 + c], acc);
    if (c == 0) atomicAdd(&gcnt[curg], cnt);
}

// ---------------- Head: out[g] = relu(mean_g @ hw1 + hb1) @ hw2 + hb2 ----------------
__global__ __launch_bounds__(128) void k_head(const float* __restrict__ gsum, const int* __restrict__ gcnt,
                                              const float* __restrict__ hw1, const float* __restrict__ hb1,
                                              const float* __restrict__ hw2, const float* __restrict__ hb2,
                                              float* __restrict__ out) {
    __shared__ float mean[128];
    __shared__ float red[128];
    int g = blockIdx.x;
    int c = threadIdx.x;
    float cntf = fmaxf((float)gcnt[g], 1.0f);
    mean[c] = gsum[g * 128 + c] / cntf;
    __syncthreads();
    float h = hb1[c];
    for (int k = 0; k < 128; k++) h = fmaf(mean[k], hw1[k * 128 + c], h);
    h = fmaxf(h, 0.f);
    red[c] = h * hw2[c];
    __syncthreads();
    for (int s = 64; s > 0; s >>= 1) {
        if (c < s) red[c] += red[c + s];
        __syncthreads();
    }
    if (c == 0) out[g] = red[0] + hb2[0];
}

// ---------------- launch ----------------
extern "C" void kernel_launch(void* const* d_in, const int* in_sizes, int n_in,
                              void* d_out, int out_size, void* d_ws, size_t ws_size,
                              hipStream_t stream) {
    const float* x   = (const float*)d_in[0];
    const int*  edge = (const int*)d_in[1];
    const int*  batch= (const int*)d_in[2];
    const float* w1  = (const float*)d_in[3];
    const float* b1  = (const float*)d_in[4];
    const float* w2  = (const float*)d_in[5];
    const float* b2  = (const float*)d_in[6];
    const float* w3  = (const float*)d_in[7];
    const float* b3  = (const float*)d_in[8];
    const float* hw1 = (const float*)d_in[9];
    const float* hb1 = (const float*)d_in[10];
    const float* hw2 = (const float*)d_in[11];
    const float* hb2 = (const float*)d_in[12];
    float* out = (float*)d_out;

    const int n = in_sizes[0] / 128;
    const int e = in_sizes[1] / 2;
    const int* row = edge;
    const int* col = edge + e;

    char* wsb = (char*)d_ws;
    size_t off = 0;
    auto alloc = [&](size_t bytes) -> void* {
        void* p = wsb + off;
        off = (off + bytes + 511) & ~size_t(511);
        return p;
    };
    float* A      = (float*)alloc((size_t)n * 128 * 4);
    float* Bb     = (float*)alloc((size_t)n * 128 * 4);
    float* dinv   = (float*)alloc((size_t)n * 4);
    int*   cnt    = (int*)  alloc((size_t)n * 4);
    int*   colptr = (int*)  alloc((size_t)(n + 1) * 4);
    int*   cursor = (int*)  alloc((size_t)n * 4);
    int*   bsum   = (int*)  alloc(512);
    int*   boff   = (int*)  alloc(512);
    int*   esrc   = (int*)  alloc((size_t)e * 4);
    float* gsum   = (float*)alloc(64 * 128 * 4);
    int*   gcnt   = (int*)  alloc(64 * 4);

    hipMemsetAsync(cnt,  0, (size_t)n * 4, stream);
    hipMemsetAsync(gsum, 0, 64 * 128 * 4, stream);
    hipMemsetAsync(gcnt, 0, 64 * 4, stream);

    k_hist<<<(e + 255) / 256, 256, 0, stream>>>(col, cnt, e);
    k_dinv<<<(n + 255) / 256, 256, 0, stream>>>(cnt, dinv, n);
    int nb = (n + 1023) / 1024;
    k_scan1<<<nb, 256, 0, stream>>>(cnt, colptr, bsum, n);
    k_scan2<<<1, 128, 0, stream>>>(bsum, boff, nb);
    k_scan3<<<(n + 1 + 255) / 256, 256, 0, stream>>>(colptr, boff, cursor, n);
    k_fill<<<(e + 255) / 256, 256, 0, stream>>>(row, col, cursor, esrc, e);

    int gb = (n + 127) / 128;
    k_gemm<<<gb, 512, 0, stream>>>(x,  w1, b1, dinv, A, n);
    k_agg <<<(n + 3) / 4, 256, 0, stream>>>(A, colptr, esrc, dinv, Bb, n);
    k_gemm<<<gb, 512, 0, stream>>>(Bb, w2, b2, dinv, A, n);
    k_agg <<<(n + 3) / 4, 256, 0, stream>>>(A, colptr, esrc, dinv, Bb, n);
    k_gemm<<<gb, 512, 0, stream>>>(Bb, w3, b3, dinv, A, n);
    k_agg <<<(n + 3) / 4, 256, 0, stream>>>(A, colptr, esrc, dinv, Bb, n);

    k_pool<<<(n + 63) / 64, 128, 0, stream>>>(Bb, batch, gsum, gcnt, n);
    k_head<<<64, 128, 0, stream>>>(gsum, gcnt, hw1, hb1, hw2, hb2, out);
}

// Round 4
// 704.784 us; speedup vs baseline: 1.4426x; 1.1565x over previous
//
#include <hip/hip_runtime.h>

typedef _Float16 f16;
typedef __attribute__((ext_vector_type(8))) _Float16 f16x8;
typedef __attribute__((ext_vector_type(4))) float f32x4;

// ---------------- CSR build ----------------

__global__ __launch_bounds__(256) void k_hist(const int* __restrict__ col, int* __restrict__ cnt, int e) {
    int i = blockIdx.x * 256 + threadIdx.x;
    if (i < e) atomicAdd(&cnt[col[i]], 1);
}

__global__ __launch_bounds__(256) void k_dinv(const int* __restrict__ cnt, float* __restrict__ dinv, int n) {
    int i = blockIdx.x * 256 + threadIdx.x;
    if (i < n) dinv[i] = rsqrtf((float)(cnt[i] + 1));  // +1 self loop
}

// block-level inclusive scan of 1024 elements (256 thr x 4)
__global__ __launch_bounds__(256) void k_scan1(const int* __restrict__ cnt, int* __restrict__ colptr,
                                               int* __restrict__ bsum, int n) {
    __shared__ int lds[256];
    int t = threadIdx.x;
    int base = blockIdx.x * 1024;
    int idx = base + t * 4;
    int4 v = make_int4(0, 0, 0, 0);
    if (idx + 3 < n) {
        v = *(const int4*)(cnt + idx);
    } else {
        if (idx     < n) v.x = cnt[idx];
        if (idx + 1 < n) v.y = cnt[idx + 1];
        if (idx + 2 < n) v.z = cnt[idx + 2];
        if (idx + 3 < n) v.w = cnt[idx + 3];
    }
    int s1 = v.x, s2 = s1 + v.y, s3 = s2 + v.z, s4 = s3 + v.w;
    lds[t] = s4;
    __syncthreads();
    for (int off = 1; off < 256; off <<= 1) {
        int mine = lds[t];
        int add  = (t >= off) ? lds[t - off] : 0;
        __syncthreads();
        lds[t] = mine + add;
        __syncthreads();
    }
    int incl = lds[t];
    int excl = incl - s4;
    if (t == 255) bsum[blockIdx.x] = incl;
    if (idx     < n) colptr[idx + 1] = excl + s1;
    if (idx + 1 < n) colptr[idx + 2] = excl + s2;
    if (idx + 2 < n) colptr[idx + 3] = excl + s3;
    if (idx + 3 < n) colptr[idx + 4] = excl + s4;
}

__global__ __launch_bounds__(128) void k_scan2(const int* __restrict__ bsum, int* __restrict__ boff, int nb) {
    __shared__ int lds[128];
    int t = threadIdx.x;
    int v = (t < nb) ? bsum[t] : 0;
    lds[t] = v;
    __syncthreads();
    for (int off = 1; off < 128; off <<= 1) {
        int mine = lds[t];
        int add  = (t >= off) ? lds[t - off] : 0;
        __syncthreads();
        lds[t] = mine + add;
        __syncthreads();
    }
    if (t < nb) boff[t] = lds[t] - v;  // exclusive
}

__global__ __launch_bounds__(256) void k_scan3(int* __restrict__ colptr, const int* __restrict__ boff,
                                               int* __restrict__ cursor, int n) {
    int j = blockIdx.x * 256 + threadIdx.x;
    if (j > n) return;
    int val;
    if (j == 0) {
        val = 0;
        colptr[0] = 0;
    } else {
        val = colptr[j] + boff[(j - 1) >> 10];
        colptr[j] = val;
    }
    if (j < n) cursor[j] = val;
}

__global__ __launch_bounds__(256) void k_fill(const int* __restrict__ row, const int* __restrict__ col,
                                              int* __restrict__ cursor, int* __restrict__ esrc, int e) {
    int i = blockIdx.x * 256 + threadIdx.x;
    if (i < e) {
        int c = col[i];
        int pos = atomicAdd(&cursor[c], 1);
        esrc[pos] = row[i];
    }
}

// ---------------- weight conversion: fp32 -> f16 hi/lo in MFMA-frag order ----------------
// frag index fi = ((ct*4 + ks)*64 + lane)*8 + j  maps to  w[k][c],
// c = ct*16 + (lane&15), k = ks*32 + (lane>>4)*8 + j.
__global__ __launch_bounds__(256) void k_wconv(const float* __restrict__ w, f16* __restrict__ whi,
                                               f16* __restrict__ wlo) {
    int fi = blockIdx.x * 256 + threadIdx.x;   // 0..16383
    int j  = fi & 7;
    int l  = (fi >> 3) & 63;
    int ks = (fi >> 9) & 3;
    int ct = fi >> 11;
    int k = ks * 32 + (l >> 4) * 8 + j;
    int c = ct * 16 + (l & 15);
    float x = w[k * 128 + c];
    f16 hi = (f16)x;
    f16 lo = (f16)(x - (float)hi);
    whi[fi] = hi;
    wlo[fi] = lo;
}

// ---------------- GEMM via fp16-split MFMA: out[r] = dinv[r] * (in[r] @ W + b) ----------------
// Block 256 thr = 4 waves (2 row-halves x 2 col-halves); tile 64 rows x 128 cols.
// No LDS. B-frags read directly from frag-ordered whi/wlo (L1/L2 resident).
// A split in-register: in = Ah + Al (f16); acc += Al*Bh + Ah*Bl + Ah*Bh.
__global__ __launch_bounds__(256) void k_gemm_mfma(const float* __restrict__ in, const f16* __restrict__ whi,
                                                   const f16* __restrict__ wlo, const float* __restrict__ bias,
                                                   const float* __restrict__ dinv, float* __restrict__ out, int n) {
    int lane = threadIdx.x & 63;
    int wid  = threadIdx.x >> 6;
    int wr = wid >> 1, wc = wid & 1;
    int rbase = blockIdx.x * 64 + wr * 32;
    int rowA = lane & 15;          // row within 16-row tile for A-frag
    int kg   = lane >> 4;          // k-group 0..3

    f32x4 acc[2][4];
    #pragma unroll
    for (int i = 0; i < 2; i++)
        #pragma unroll
        for (int j = 0; j < 4; j++) acc[i][j] = (f32x4){0.f, 0.f, 0.f, 0.f};

    #pragma unroll
    for (int ks = 0; ks < 4; ks++) {
        // A fragments: rows rbase + rt*16 + rowA, k = ks*32 + kg*8 + j
        f16x8 ah[2], al[2];
        #pragma unroll
        for (int rt = 0; rt < 2; rt++) {
            int r = rbase + rt * 16 + rowA;
            int k0 = ks * 32 + kg * 8;
            float4 x0 = make_float4(0.f, 0.f, 0.f, 0.f), x1 = x0;
            if (r < n) {
                const float4* p = (const float4*)(in + (size_t)r * 128 + k0);
                x0 = p[0];
                x1 = p[1];
            }
            float xs[8] = {x0.x, x0.y, x0.z, x0.w, x1.x, x1.y, x1.z, x1.w};
            #pragma unroll
            for (int j = 0; j < 8; j++) {
                f16 h = (f16)xs[j];
                ah[rt][j] = h;
                al[rt][j] = (f16)(xs[j] - (float)h);
            }
        }
        // B fragments: 4 col-tiles for this wave's col half
        f16x8 bh[4], bl[4];
        #pragma unroll
        for (int ct = 0; ct < 4; ct++) {
            int g = ((wc * 4 + ct) * 4 + ks);
            size_t idx = (size_t)(g * 64 + lane) * 8;
            bh[ct] = *(const f16x8*)(whi + idx);
            bl[ct] = *(const f16x8*)(wlo + idx);
        }
        #pragma unroll
        for (int rt = 0; rt < 2; rt++)
            #pragma unroll
            for (int ct = 0; ct < 4; ct++) {
                acc[rt][ct] = __builtin_amdgcn_mfma_f32_16x16x32_f16(al[rt], bh[ct], acc[rt][ct], 0, 0, 0);
                acc[rt][ct] = __builtin_amdgcn_mfma_f32_16x16x32_f16(ah[rt], bl[ct], acc[rt][ct], 0, 0, 0);
                acc[rt][ct] = __builtin_amdgcn_mfma_f32_16x16x32_f16(ah[rt], bh[ct], acc[rt][ct], 0, 0, 0);
            }
    }

    // epilogue: D layout col=lane&15, row=(lane>>4)*4+reg
    int cl = lane & 15;
    int rq = lane >> 4;
    #pragma unroll
    for (int rt = 0; rt < 2; rt++) {
        #pragma unroll
        for (int ct = 0; ct < 4; ct++) {
            int c = wc * 64 + ct * 16 + cl;
            float bv = bias[c];
            #pragma unroll
            for (int reg = 0; reg < 4; reg++) {
                int r = rbase + rt * 16 + rq * 4 + reg;
                if (r < n) {
                    float dv = dinv[r];
                    out[(size_t)r * 128 + c] = dv * (acc[rt][ct][reg] + bv);
                }
            }
        }
    }
}

// ---------------- Aggregation: B[v] = relu(dinv[v] * (A[v] + sum_{src} A[src])) ----------------
__global__ __launch_bounds__(256) void k_agg(const float* __restrict__ A, const int* __restrict__ colptr,
                                             const int* __restrict__ esrc, const float* __restrict__ dinv,
                                             float* __restrict__ B, int n) {
    int lane = threadIdx.x & 63;
    int v = blockIdx.x * 4 + (threadIdx.x >> 6);
    if (v >= n) return;
    const float2* __restrict__ A2 = (const float2*)A;
    int p0 = colptr[v], p1 = colptr[v + 1];
    float2 acc = A2[(size_t)v * 64 + lane];  // self loop (row already dinv[v]-scaled)
    int p = p0;
    for (; p + 4 <= p1; p += 4) {
        int s0 = esrc[p];
        int s1 = esrc[p + 1];
        int s2 = esrc[p + 2];
        int s3 = esrc[p + 3];
        float2 v0 = A2[(size_t)s0 * 64 + lane];
        float2 v1 = A2[(size_t)s1 * 64 + lane];
        float2 v2 = A2[(size_t)s2 * 64 + lane];
        float2 v3 = A2[(size_t)s3 * 64 + lane];
        acc.x += v0.x; acc.y += v0.y;
        acc.x += v1.x; acc.y += v1.y;
        acc.x += v2.x; acc.y += v2.y;
        acc.x += v3.x; acc.y += v3.y;
    }
    for (; p < p1; ++p) {
        int s = esrc[p];
        float2 vv = A2[(size_t)s * 64 + lane];
        acc.x += vv.x; acc.y += vv.y;
    }
    float d = dinv[v];
    float ox = fmaxf(d * acc.x, 0.f);
    float oy = fmaxf(d * acc.y, 0.f);
    ((float2*)B)[(size_t)v * 64 + lane] = make_float2(ox, oy);
}

// ---------------- Pooling (batch is sorted) ----------------
__global__ __launch_bounds__(128) void k_pool(const float* __restrict__ B, const int* __restrict__ batch,
                                              float* __restrict__ gsum, int* __restrict__ gcnt, int n) {
    int c = threadIdx.x;
    int base = blockIdx.x * 64;
    if (base >= n) return;
    int end = min(base + 64, n);
    int curg = batch[base];
    float acc = 0.f;
    int cnt = 0;
    for (int i = base; i < end; i++) {
        int g = batch[i];
        if (g != curg) {
            atomicAdd(&gsum[curg * 128 + c], acc);
            if (c == 0) atomicAdd(&gcnt[curg], cnt);
            acc = 0.f; cnt = 0; curg = g;
        }
        acc += B[i * 128 + c];
        cnt++;
    }
    atomicAdd(&gsum[curg * 128 + c], acc);
    if (c == 0) atomicAdd(&gcnt[curg], cnt);
}

// ---------------- Head: out[g] = relu(mean_g @ hw1 + hb1) @ hw2 + hb2 ----------------
__global__ __launch_bounds__(128) void k_head(const float* __restrict__ gsum, const int* __restrict__ gcnt,
                                              const float* __restrict__ hw1, const float* __restrict__ hb1,
                                              const float* __restrict__ hw2, const float* __restrict__ hb2,
                                              float* __restrict__ out) {
    __shared__ float mean[128];
    __shared__ float red[128];
    int g = blockIdx.x;
    int c = threadIdx.x;
    float cntf = fmaxf((float)gcnt[g], 1.0f);
    mean[c] = gsum[g * 128 + c] / cntf;
    __syncthreads();
    float h = hb1[c];
    for (int k = 0; k < 128; k++) h = fmaf(mean[k], hw1[k * 128 + c], h);
    h = fmaxf(h, 0.f);
    red[c] = h * hw2[c];
    __syncthreads();
    for (int s = 64; s > 0; s >>= 1) {
        if (c < s) red[c] += red[c + s];
        __syncthreads();
    }
    if (c == 0) out[g] = red[0] + hb2[0];
}

// ---------------- launch ----------------
extern "C" void kernel_launch(void* const* d_in, const int* in_sizes, int n_in,
                              void* d_out, int out_size, void* d_ws, size_t ws_size,
                              hipStream_t stream) {
    const float* x   = (const float*)d_in[0];
    const int*  edge = (const int*)d_in[1];
    const int*  batch= (const int*)d_in[2];
    const float* w1  = (const float*)d_in[3];
    const float* b1  = (const float*)d_in[4];
    const float* w2  = (const float*)d_in[5];
    const float* b2  = (const float*)d_in[6];
    const float* w3  = (const float*)d_in[7];
    const float* b3  = (const float*)d_in[8];
    const float* hw1 = (const float*)d_in[9];
    const float* hb1 = (const float*)d_in[10];
    const float* hw2 = (const float*)d_in[11];
    const float* hb2 = (const float*)d_in[12];
    float* out = (float*)d_out;

    const int n = in_sizes[0] / 128;
    const int e = in_sizes[1] / 2;
    const int* row = edge;
    const int* col = edge + e;

    char* wsb = (char*)d_ws;
    size_t off = 0;
    auto alloc = [&](size_t bytes) -> void* {
        void* p = wsb + off;
        off = (off + bytes + 511) & ~size_t(511);
        return p;
    };
    float* A      = (float*)alloc((size_t)n * 128 * 4);
    float* Bb     = (float*)alloc((size_t)n * 128 * 4);
    float* dinv   = (float*)alloc((size_t)n * 4);
    int*   cnt    = (int*)  alloc((size_t)n * 4);
    int*   colptr = (int*)  alloc((size_t)(n + 1) * 4);
    int*   cursor = (int*)  alloc((size_t)n * 4);
    int*   bsum   = (int*)  alloc(512);
    int*   boff   = (int*)  alloc(512);
    int*   esrc   = (int*)  alloc((size_t)e * 4);
    float* gsum   = (float*)alloc(64 * 128 * 4);
    int*   gcnt   = (int*)  alloc(64 * 4);
    f16*   whi    = (f16*)  alloc(3 * 16384 * 2);
    f16*   wlo    = (f16*)  alloc(3 * 16384 * 2);

    hipMemsetAsync(cnt,  0, (size_t)n * 4, stream);
    hipMemsetAsync(gsum, 0, 64 * 128 * 4, stream);
    hipMemsetAsync(gcnt, 0, 64 * 4, stream);

    // weight conversion (tiny)
    k_wconv<<<64, 256, 0, stream>>>(w1, whi,             wlo);
    k_wconv<<<64, 256, 0, stream>>>(w2, whi + 16384,     wlo + 16384);
    k_wconv<<<64, 256, 0, stream>>>(w3, whi + 2 * 16384, wlo + 2 * 16384);

    k_hist<<<(e + 255) / 256, 256, 0, stream>>>(col, cnt, e);
    k_dinv<<<(n + 255) / 256, 256, 0, stream>>>(cnt, dinv, n);
    int nb = (n + 1023) / 1024;
    k_scan1<<<nb, 256, 0, stream>>>(cnt, colptr, bsum, n);
    k_scan2<<<1, 128, 0, stream>>>(bsum, boff, nb);
    k_scan3<<<(n + 1 + 255) / 256, 256, 0, stream>>>(colptr, boff, cursor, n);
    k_fill<<<(e + 255) / 256, 256, 0, stream>>>(row, col, cursor, esrc, e);

    int gb = (n + 63) / 64;
    k_gemm_mfma<<<gb, 256, 0, stream>>>(x,  whi,             wlo,             b1, dinv, A, n);
    k_agg <<<(n + 3) / 4, 256, 0, stream>>>(A, colptr, esrc, dinv, Bb, n);
    k_gemm_mfma<<<gb, 256, 0, stream>>>(Bb, whi + 16384,     wlo + 16384,     b2, dinv, A, n);
    k_agg <<<(n + 3) / 4, 256, 0, stream>>>(A, colptr, esrc, dinv, Bb, n);
    k_gemm_mfma<<<gb, 256, 0, stream>>>(Bb, whi + 2 * 16384, wlo + 2 * 16384, b3, dinv, A, n);
    k_agg <<<(n + 3) / 4, 256, 0, stream>>>(A, colptr, esrc, dinv, Bb, n);

    k_pool<<<(n + 63) / 64, 128, 0, stream>>>(Bb, batch, gsum, gcnt, n);
    k_head<<<64, 128, 0, stream>>>(gsum, gcnt, hw1, hb1, hw2, hb2, out);
}

// Round 5
// 655.740 us; speedup vs baseline: 1.5505x; 1.0748x over previous
//
#include <hip/hip_runtime.h>

typedef _Float16 f16;
typedef __attribute__((ext_vector_type(8))) _Float16 f16x8;
typedef __attribute__((ext_vector_type(4))) float f32x4;

#define BSH 9   // 512 nodes per bucket

// ---------------- CSR build ----------------

__global__ __launch_bounds__(256) void k_hist(const int* __restrict__ col, int* __restrict__ cnt, int e) {
    int i = blockIdx.x * 256 + threadIdx.x;
    if (i < e) atomicAdd(&cnt[col[i]], 1);
}

__global__ __launch_bounds__(256) void k_dinv(const int* __restrict__ cnt, float* __restrict__ dinv, int n) {
    int i = blockIdx.x * 256 + threadIdx.x;
    if (i < n) dinv[i] = rsqrtf((float)(cnt[i] + 1));  // +1 self loop
}

// block-level inclusive scan of 1024 elements (256 thr x 4)
__global__ __launch_bounds__(256) void k_scan1(const int* __restrict__ cnt, int* __restrict__ colptr,
                                               int* __restrict__ bsum, int n) {
    __shared__ int lds[256];
    int t = threadIdx.x;
    int base = blockIdx.x * 1024;
    int idx = base + t * 4;
    int4 v = make_int4(0, 0, 0, 0);
    if (idx + 3 < n) {
        v = *(const int4*)(cnt + idx);
    } else {
        if (idx     < n) v.x = cnt[idx];
        if (idx + 1 < n) v.y = cnt[idx + 1];
        if (idx + 2 < n) v.z = cnt[idx + 2];
        if (idx + 3 < n) v.w = cnt[idx + 3];
    }
    int s1 = v.x, s2 = s1 + v.y, s3 = s2 + v.z, s4 = s3 + v.w;
    lds[t] = s4;
    __syncthreads();
    for (int off = 1; off < 256; off <<= 1) {
        int mine = lds[t];
        int add  = (t >= off) ? lds[t - off] : 0;
        __syncthreads();
        lds[t] = mine + add;
        __syncthreads();
    }
    int incl = lds[t];
    int excl = incl - s4;
    if (t == 255) bsum[blockIdx.x] = incl;
    if (idx     < n) colptr[idx + 1] = excl + s1;
    if (idx + 1 < n) colptr[idx + 2] = excl + s2;
    if (idx + 2 < n) colptr[idx + 3] = excl + s3;
    if (idx + 3 < n) colptr[idx + 4] = excl + s4;
}

__global__ __launch_bounds__(128) void k_scan2(const int* __restrict__ bsum, int* __restrict__ boff, int nb) {
    __shared__ int lds[128];
    int t = threadIdx.x;
    int v = (t < nb) ? bsum[t] : 0;
    lds[t] = v;
    __syncthreads();
    for (int off = 1; off < 128; off <<= 1) {
        int mine = lds[t];
        int add  = (t >= off) ? lds[t - off] : 0;
        __syncthreads();
        lds[t] = mine + add;
        __syncthreads();
    }
    if (t < nb) boff[t] = lds[t] - v;  // exclusive
}

__global__ __launch_bounds__(256) void k_scan3(int* __restrict__ colptr, const int* __restrict__ boff,
                                               int* __restrict__ cursor, int n) {
    int j = blockIdx.x * 256 + threadIdx.x;
    if (j > n) return;
    int val;
    if (j == 0) {
        val = 0;
        colptr[0] = 0;
    } else {
        val = colptr[j] + boff[(j - 1) >> 10];
        colptr[j] = val;
    }
    if (j < n) cursor[j] = val;
}

// bucket cursors: bcur[b] = colptr[min(b<<BSH, n)]  (256 entries, extras clamp to e)
__global__ __launch_bounds__(256) void k_binit(const int* __restrict__ colptr, int* __restrict__ bcur, int n) {
    int t = threadIdx.x;
    int node = min(t << BSH, n);
    bcur[t] = colptr[node];
}

// ---------------- bucket partition: edges -> ebuck grouped by (col >> BSH) ----------------
// 4096 edges per WG; LDS histogram+scan; stage sorted-by-bucket in LDS; copy out
// with consecutive threads -> consecutive global addresses (coalesced runs).
__global__ __launch_bounds__(256) void k_part(const int* __restrict__ row, const int* __restrict__ col,
                                              int* __restrict__ bcur, int2* __restrict__ ebuck, int e) {
    __shared__ int hist[256];
    __shared__ int excl[256];
    __shared__ int rbase[256];
    __shared__ int2 stage[4096];
    int t = threadIdx.x;
    int wgbase = blockIdx.x * 4096;
    int total = min(4096, e - wgbase);

    hist[t] = 0;
    __syncthreads();

    int2 myrc[16];
    int  myrank[16];
    #pragma unroll
    for (int k = 0; k < 16; k++) {
        int i = wgbase + k * 256 + t;
        int2 rc = make_int2(0, 0);
        int rnk = 0;
        if (i < e) {
            rc.x = row[i];
            rc.y = col[i];
            rnk = atomicAdd(&hist[rc.y >> BSH], 1);
        }
        myrc[k] = rc;
        myrank[k] = rnk;
    }
    __syncthreads();

    // exclusive scan of hist into excl
    excl[t] = hist[t];
    __syncthreads();
    for (int off = 1; off < 256; off <<= 1) {
        int mine = excl[t];
        int add  = (t >= off) ? excl[t - off] : 0;
        __syncthreads();
        excl[t] = mine + add;
        __syncthreads();
    }
    excl[t] -= hist[t];
    // reserve global range for this WG's share of bucket t
    rbase[t] = (hist[t] > 0) ? atomicAdd(&bcur[t], hist[t]) : 0;
    __syncthreads();

    // stage edges sorted by bucket
    #pragma unroll
    for (int k = 0; k < 16; k++) {
        int i = wgbase + k * 256 + t;
        if (i < e) stage[excl[myrc[k].y >> BSH] + myrank[k]] = myrc[k];
    }
    __syncthreads();

    // copy out: consecutive j -> consecutive addresses within each bucket run
    for (int j = t; j < total; j += 256) {
        int2 rc = stage[j];
        int b = rc.y >> BSH;
        ebuck[rbase[b] + (j - excl[b])] = rc;
    }
}

// ---------------- fill esrc from bucketed edges (cursor/esrc windows are cache-resident) ----------------
__global__ __launch_bounds__(256) void k_fill2(const int2* __restrict__ ebuck, const int* __restrict__ colptr,
                                               int* __restrict__ cursor, int* __restrict__ esrc, int n) {
    int b = blockIdx.x >> 2;
    int sub = blockIdx.x & 3;
    int lo_node = b << BSH;
    int hi_node = min((b + 1) << BSH, n);
    if (lo_node >= n) return;
    int e_lo = colptr[lo_node], e_hi = colptr[hi_node];
    for (int i = e_lo + sub * 256 + threadIdx.x; i < e_hi; i += 1024) {
        int2 rc = ebuck[i];
        int pos = atomicAdd(&cursor[rc.y], 1);
        esrc[pos] = rc.x;
    }
}

// ---------------- weight conversion: fp32 -> f16 hi/lo in MFMA-frag order ----------------
__global__ __launch_bounds__(256) void k_wconv(const float* __restrict__ w, f16* __restrict__ whi,
                                               f16* __restrict__ wlo) {
    int fi = blockIdx.x * 256 + threadIdx.x;   // 0..16383
    int j  = fi & 7;
    int l  = (fi >> 3) & 63;
    int ks = (fi >> 9) & 3;
    int ct = fi >> 11;
    int k = ks * 32 + (l >> 4) * 8 + j;
    int c = ct * 16 + (l & 15);
    float x = w[k * 128 + c];
    f16 hi = (f16)x;
    f16 lo = (f16)(x - (float)hi);
    whi[fi] = hi;
    wlo[fi] = lo;
}

// ---------------- GEMM via fp16-split MFMA: out[r] = dinv[r] * (in[r] @ W + b) ----------------
__global__ __launch_bounds__(256) void k_gemm_mfma(const float* __restrict__ in, const f16* __restrict__ whi,
                                                   const f16* __restrict__ wlo, const float* __restrict__ bias,
                                                   const float* __restrict__ dinv, float* __restrict__ out, int n) {
    int lane = threadIdx.x & 63;
    int wid  = threadIdx.x >> 6;
    int wr = wid >> 1, wc = wid & 1;
    int rbase = blockIdx.x * 64 + wr * 32;
    int rowA = lane & 15;
    int kg   = lane >> 4;

    f32x4 acc[2][4];
    #pragma unroll
    for (int i = 0; i < 2; i++)
        #pragma unroll
        for (int j = 0; j < 4; j++) acc[i][j] = (f32x4){0.f, 0.f, 0.f, 0.f};

    #pragma unroll
    for (int ks = 0; ks < 4; ks++) {
        f16x8 ah[2], al[2];
        #pragma unroll
        for (int rt = 0; rt < 2; rt++) {
            int r = rbase + rt * 16 + rowA;
            int k0 = ks * 32 + kg * 8;
            float4 x0 = make_float4(0.f, 0.f, 0.f, 0.f), x1 = x0;
            if (r < n) {
                const float4* p = (const float4*)(in + (size_t)r * 128 + k0);
                x0 = p[0];
                x1 = p[1];
            }
            float xs[8] = {x0.x, x0.y, x0.z, x0.w, x1.x, x1.y, x1.z, x1.w};
            #pragma unroll
            for (int j = 0; j < 8; j++) {
                f16 h = (f16)xs[j];
                ah[rt][j] = h;
                al[rt][j] = (f16)(xs[j] - (float)h);
            }
        }
        f16x8 bh[4], bl[4];
        #pragma unroll
        for (int ct = 0; ct < 4; ct++) {
            int g = ((wc * 4 + ct) * 4 + ks);
            size_t idx = (size_t)(g * 64 + lane) * 8;
            bh[ct] = *(const f16x8*)(whi + idx);
            bl[ct] = *(const f16x8*)(wlo + idx);
        }
        #pragma unroll
        for (int rt = 0; rt < 2; rt++)
            #pragma unroll
            for (int ct = 0; ct < 4; ct++) {
                acc[rt][ct] = __builtin_amdgcn_mfma_f32_16x16x32_f16(al[rt], bh[ct], acc[rt][ct], 0, 0, 0);
                acc[rt][ct] = __builtin_amdgcn_mfma_f32_16x16x32_f16(ah[rt], bl[ct], acc[rt][ct], 0, 0, 0);
                acc[rt][ct] = __builtin_amdgcn_mfma_f32_16x16x32_f16(ah[rt], bh[ct], acc[rt][ct], 0, 0, 0);
            }
    }

    int cl = lane & 15;
    int rq = lane >> 4;
    #pragma unroll
    for (int rt = 0; rt < 2; rt++) {
        #pragma unroll
        for (int ct = 0; ct < 4; ct++) {
            int c = wc * 64 + ct * 16 + cl;
            float bv = bias[c];
            #pragma unroll
            for (int reg = 0; reg < 4; reg++) {
                int r = rbase + rt * 16 + rq * 4 + reg;
                if (r < n) {
                    float dv = dinv[r];
                    out[(size_t)r * 128 + c] = dv * (acc[rt][ct][reg] + bv);
                }
            }
        }
    }
}

// ---------------- Aggregation: B[v] = relu(dinv[v] * (A[v] + sum_{src} A[src])) ----------------
// One wave per node, float2 per lane; 8-wide load prefetch, strictly sequential adds.
__global__ __launch_bounds__(256) void k_agg(const float* __restrict__ A, const int* __restrict__ colptr,
                                             const int* __restrict__ esrc, const float* __restrict__ dinv,
                                             float* __restrict__ B, int n) {
    int lane = threadIdx.x & 63;
    int v = blockIdx.x * 4 + (threadIdx.x >> 6);
    if (v >= n) return;
    const float2* __restrict__ A2 = (const float2*)A;
    int p0 = colptr[v], p1 = colptr[v + 1];
    float2 acc = A2[(size_t)v * 64 + lane];  // self loop (row already dinv[v]-scaled)
    int p = p0;
    for (; p + 8 <= p1; p += 8) {
        int s0 = esrc[p];
        int s1 = esrc[p + 1];
        int s2 = esrc[p + 2];
        int s3 = esrc[p + 3];
        int s4 = esrc[p + 4];
        int s5 = esrc[p + 5];
        int s6 = esrc[p + 6];
        int s7 = esrc[p + 7];
        float2 v0 = A2[(size_t)s0 * 64 + lane];
        float2 v1 = A2[(size_t)s1 * 64 + lane];
        float2 v2 = A2[(size_t)s2 * 64 + lane];
        float2 v3 = A2[(size_t)s3 * 64 + lane];
        float2 v4 = A2[(size_t)s4 * 64 + lane];
        float2 v5 = A2[(size_t)s5 * 64 + lane];
        float2 v6 = A2[(size_t)s6 * 64 + lane];
        float2 v7 = A2[(size_t)s7 * 64 + lane];
        acc.x += v0.x; acc.y += v0.y;
        acc.x += v1.x; acc.y += v1.y;
        acc.x += v2.x; acc.y += v2.y;
        acc.x += v3.x; acc.y += v3.y;
        acc.x += v4.x; acc.y += v4.y;
        acc.x += v5.x; acc.y += v5.y;
        acc.x += v6.x; acc.y += v6.y;
        acc.x += v7.x; acc.y += v7.y;
    }
    for (; p < p1; ++p) {
        int s = esrc[p];
        float2 vv = A2[(size_t)s * 64 + lane];
        acc.x += vv.x; acc.y += vv.y;
    }
    float d = dinv[v];
    float ox = fmaxf(d * acc.x, 0.f);
    float oy = fmaxf(d * acc.y, 0.f);
    ((float2*)B)[(size_t)v * 64 + lane] = make_float2(ox, oy);
}

// ---------------- Pooling (batch is sorted) ----------------
__global__ __launch_bounds__(128) void k_pool(const float* __restrict__ B, const int* __restrict__ batch,
                                              float* __restrict__ gsum, int* __restrict__ gcnt, int n) {
    int c = threadIdx.x;
    int base = blockIdx.x * 64;
    if (base >= n) return;
    int end = min(base + 64, n);
    int curg = batch[base];
    float acc = 0.f;
    int cnt = 0;
    for (int i = base; i < end; i++) {
        int g = batch[i];
        if (g != curg) {
            atomicAdd(&gsum[curg * 128 + c], acc);
            if (c == 0) atomicAdd(&gcnt[curg], cnt);
            acc = 0.f; cnt = 0; curg = g;
        }
        acc += B[i * 128 + c];
        cnt++;
    }
    atomicAdd(&gsum[curg * 128 + c], acc);
    if (c == 0) atomicAdd(&gcnt[curg], cnt);
}

// ---------------- Head ----------------
__global__ __launch_bounds__(128) void k_head(const float* __restrict__ gsum, const int* __restrict__ gcnt,
                                              const float* __restrict__ hw1, const float* __restrict__ hb1,
                                              const float* __restrict__ hw2, const float* __restrict__ hb2,
                                              float* __restrict__ out) {
    __shared__ float mean[128];
    __shared__ float red[128];
    int g = blockIdx.x;
    int c = threadIdx.x;
    float cntf = fmaxf((float)gcnt[g], 1.0f);
    mean[c] = gsum[g * 128 + c] / cntf;
    __syncthreads();
    float h = hb1[c];
    for (int k = 0; k < 128; k++) h = fmaf(mean[k], hw1[k * 128 + c], h);
    h = fmaxf(h, 0.f);
    red[c] = h * hw2[c];
    __syncthreads();
    for (int s = 64; s > 0; s >>= 1) {
        if (c < s) red[c] += red[c + s];
        __syncthreads();
    }
    if (c == 0) out[g] = red[0] + hb2[0];
}

// ---------------- launch ----------------
extern "C" void kernel_launch(void* const* d_in, const int* in_sizes, int n_in,
                              void* d_out, int out_size, void* d_ws, size_t ws_size,
                              hipStream_t stream) {
    const float* x   = (const float*)d_in[0];
    const int*  edge = (const int*)d_in[1];
    const int*  batch= (const int*)d_in[2];
    const float* w1  = (const float*)d_in[3];
    const float* b1  = (const float*)d_in[4];
    const float* w2  = (const float*)d_in[5];
    const float* b2  = (const float*)d_in[6];
    const float* w3  = (const float*)d_in[7];
    const float* b3  = (const float*)d_in[8];
    const float* hw1 = (const float*)d_in[9];
    const float* hb1 = (const float*)d_in[10];
    const float* hw2 = (const float*)d_in[11];
    const float* hb2 = (const float*)d_in[12];
    float* out = (float*)d_out;

    const int n = in_sizes[0] / 128;
    const int e = in_sizes[1] / 2;
    const int* row = edge;
    const int* col = edge + e;

    char* wsb = (char*)d_ws;
    size_t off = 0;
    auto alloc = [&](size_t bytes) -> void* {
        void* p = wsb + off;
        off = (off + bytes + 511) & ~size_t(511);
        return p;
    };
    float* A      = (float*)alloc((size_t)n * 128 * 4);
    float* Bb     = (float*)alloc((size_t)n * 128 * 4);
    float* dinv   = (float*)alloc((size_t)n * 4);
    int*   cnt    = (int*)  alloc((size_t)n * 4);
    int*   colptr = (int*)  alloc((size_t)(n + 1) * 4);
    int*   cursor = (int*)  alloc((size_t)n * 4);
    int*   bsum   = (int*)  alloc(512);
    int*   boff   = (int*)  alloc(512);
    int*   bcur   = (int*)  alloc(1024);
    int*   esrc   = (int*)  alloc((size_t)e * 4);
    float* gsum   = (float*)alloc(64 * 128 * 4);
    int*   gcnt   = (int*)  alloc(64 * 4);
    f16*   whi    = (f16*)  alloc(3 * 16384 * 2);
    f16*   wlo    = (f16*)  alloc(3 * 16384 * 2);
    // ebuck aliases Bb: only live between k_part and k_fill2, before the first k_agg writes Bb
    int2*  ebuck  = (int2*)Bb;

    hipMemsetAsync(cnt,  0, (size_t)n * 4, stream);
    hipMemsetAsync(gsum, 0, 64 * 128 * 4, stream);
    hipMemsetAsync(gcnt, 0, 64 * 4, stream);

    k_wconv<<<64, 256, 0, stream>>>(w1, whi,             wlo);
    k_wconv<<<64, 256, 0, stream>>>(w2, whi + 16384,     wlo + 16384);
    k_wconv<<<64, 256, 0, stream>>>(w3, whi + 2 * 16384, wlo + 2 * 16384);

    k_hist<<<(e + 255) / 256, 256, 0, stream>>>(col, cnt, e);
    k_dinv<<<(n + 255) / 256, 256, 0, stream>>>(cnt, dinv, n);
    int nb = (n + 1023) / 1024;
    k_scan1<<<nb, 256, 0, stream>>>(cnt, colptr, bsum, n);
    k_scan2<<<1, 128, 0, stream>>>(bsum, boff, nb);
    k_scan3<<<(n + 1 + 255) / 256, 256, 0, stream>>>(colptr, boff, cursor, n);
    k_binit<<<1, 256, 0, stream>>>(colptr, bcur, n);
    k_part<<<(e + 4095) / 4096, 256, 0, stream>>>(row, col, bcur, ebuck, e);
    int nbk = (n + (1 << BSH) - 1) >> BSH;
    k_fill2<<<nbk * 4, 256, 0, stream>>>(ebuck, colptr, cursor, esrc, n);

    int gb = (n + 63) / 64;
    k_gemm_mfma<<<gb, 256, 0, stream>>>(x,  whi,             wlo,             b1, dinv, A, n);
    k_agg <<<(n + 3) / 4, 256, 0, stream>>>(A, colptr, esrc, dinv, Bb, n);
    k_gemm_mfma<<<gb, 256, 0, stream>>>(Bb, whi + 16384,     wlo + 16384,     b2, dinv, A, n);
    k_agg <<<(n + 3) / 4, 256, 0, stream>>>(A, colptr, esrc, dinv, Bb, n);
    k_gemm_mfma<<<gb, 256, 0, stream>>>(Bb, whi + 2 * 16384, wlo + 2 * 16384, b3, dinv, A, n);
    k_agg <<<(n + 3) / 4, 256, 0, stream>>>(A, colptr, esrc, dinv, Bb, n);

    k_pool<<<(n + 63) / 64, 128, 0, stream>>>(Bb, batch, gsum, gcnt, n);
    k_head<<<64, 128, 0, stream>>>(gsum, gcnt, hw1, hb1, hw2, hb2, out);
}

// Round 6
// 518.639 us; speedup vs baseline: 1.9604x; 1.2643x over previous
//
#include <hip/hip_runtime.h>

typedef _Float16 f16;
typedef __attribute__((ext_vector_type(2))) _Float16 f16x2;
typedef __attribute__((ext_vector_type(8))) _Float16 f16x8;
typedef __attribute__((ext_vector_type(4))) float f32x4;

#define BSH 9   // 512 nodes per bucket

// ---------------- CSR build ----------------

__global__ __launch_bounds__(256) void k_hist(const int* __restrict__ col, int* __restrict__ cnt, int e) {
    int i = blockIdx.x * 256 + threadIdx.x;
    if (i < e) atomicAdd(&cnt[col[i]], 1);
}

__global__ __launch_bounds__(256) void k_dinv(const int* __restrict__ cnt, float* __restrict__ dinv, int n) {
    int i = blockIdx.x * 256 + threadIdx.x;
    if (i < n) dinv[i] = rsqrtf((float)(cnt[i] + 1));  // +1 self loop
}

// block-level inclusive scan of 1024 elements (256 thr x 4)
__global__ __launch_bounds__(256) void k_scan1(const int* __restrict__ cnt, int* __restrict__ colptr,
                                               int* __restrict__ bsum, int n) {
    __shared__ int lds[256];
    int t = threadIdx.x;
    int base = blockIdx.x * 1024;
    int idx = base + t * 4;
    int4 v = make_int4(0, 0, 0, 0);
    if (idx + 3 < n) {
        v = *(const int4*)(cnt + idx);
    } else {
        if (idx     < n) v.x = cnt[idx];
        if (idx + 1 < n) v.y = cnt[idx + 1];
        if (idx + 2 < n) v.z = cnt[idx + 2];
        if (idx + 3 < n) v.w = cnt[idx + 3];
    }
    int s1 = v.x, s2 = s1 + v.y, s3 = s2 + v.z, s4 = s3 + v.w;
    lds[t] = s4;
    __syncthreads();
    for (int off = 1; off < 256; off <<= 1) {
        int mine = lds[t];
        int add  = (t >= off) ? lds[t - off] : 0;
        __syncthreads();
        lds[t] = mine + add;
        __syncthreads();
    }
    int incl = lds[t];
    int excl = incl - s4;
    if (t == 255) bsum[blockIdx.x] = incl;
    if (idx     < n) colptr[idx + 1] = excl + s1;
    if (idx + 1 < n) colptr[idx + 2] = excl + s2;
    if (idx + 2 < n) colptr[idx + 3] = excl + s3;
    if (idx + 3 < n) colptr[idx + 4] = excl + s4;
}

__global__ __launch_bounds__(128) void k_scan2(const int* __restrict__ bsum, int* __restrict__ boff, int nb) {
    __shared__ int lds[128];
    int t = threadIdx.x;
    int v = (t < nb) ? bsum[t] : 0;
    lds[t] = v;
    __syncthreads();
    for (int off = 1; off < 128; off <<= 1) {
        int mine = lds[t];
        int add  = (t >= off) ? lds[t - off] : 0;
        __syncthreads();
        lds[t] = mine + add;
        __syncthreads();
    }
    if (t < nb) boff[t] = lds[t] - v;  // exclusive
}

__global__ __launch_bounds__(256) void k_scan3(int* __restrict__ colptr, const int* __restrict__ boff,
                                               int* __restrict__ cursor, int n) {
    int j = blockIdx.x * 256 + threadIdx.x;
    if (j > n) return;
    int val;
    if (j == 0) {
        val = 0;
        colptr[0] = 0;
    } else {
        val = colptr[j] + boff[(j - 1) >> 10];
        colptr[j] = val;
    }
    if (j < n) cursor[j] = val;
}

// bucket cursors: bcur[b] = colptr[min(b<<BSH, n)]
__global__ __launch_bounds__(256) void k_binit(const int* __restrict__ colptr, int* __restrict__ bcur, int n) {
    int t = threadIdx.x;
    int node = min(t << BSH, n);
    bcur[t] = colptr[node];
}

// ---------------- bucket partition: edges -> ebuck grouped by (col >> BSH) ----------------
__global__ __launch_bounds__(256) void k_part(const int* __restrict__ row, const int* __restrict__ col,
                                              int* __restrict__ bcur, int2* __restrict__ ebuck, int e) {
    __shared__ int hist[256];
    __shared__ int excl[256];
    __shared__ int rbase[256];
    __shared__ int2 stage[4096];
    int t = threadIdx.x;
    int wgbase = blockIdx.x * 4096;
    int total = min(4096, e - wgbase);

    hist[t] = 0;
    __syncthreads();

    int2 myrc[16];
    int  myrank[16];
    #pragma unroll
    for (int k = 0; k < 16; k++) {
        int i = wgbase + k * 256 + t;
        int2 rc = make_int2(0, 0);
        int rnk = 0;
        if (i < e) {
            rc.x = row[i];
            rc.y = col[i];
            rnk = atomicAdd(&hist[rc.y >> BSH], 1);
        }
        myrc[k] = rc;
        myrank[k] = rnk;
    }
    __syncthreads();

    excl[t] = hist[t];
    __syncthreads();
    for (int off = 1; off < 256; off <<= 1) {
        int mine = excl[t];
        int add  = (t >= off) ? excl[t - off] : 0;
        __syncthreads();
        excl[t] = mine + add;
        __syncthreads();
    }
    excl[t] -= hist[t];
    rbase[t] = (hist[t] > 0) ? atomicAdd(&bcur[t], hist[t]) : 0;
    __syncthreads();

    #pragma unroll
    for (int k = 0; k < 16; k++) {
        int i = wgbase + k * 256 + t;
        if (i < e) stage[excl[myrc[k].y >> BSH] + myrank[k]] = myrc[k];
    }
    __syncthreads();

    for (int j = t; j < total; j += 256) {
        int2 rc = stage[j];
        int b = rc.y >> BSH;
        ebuck[rbase[b] + (j - excl[b])] = rc;
    }
}

// ---------------- fill esrc from bucketed edges ----------------
__global__ __launch_bounds__(256) void k_fill2(const int2* __restrict__ ebuck, const int* __restrict__ colptr,
                                               int* __restrict__ cursor, int* __restrict__ esrc, int n) {
    int b = blockIdx.x >> 2;
    int sub = blockIdx.x & 3;
    int lo_node = b << BSH;
    int hi_node = min((b + 1) << BSH, n);
    if (lo_node >= n) return;
    int e_lo = colptr[lo_node], e_hi = colptr[hi_node];
    for (int i = e_lo + sub * 256 + threadIdx.x; i < e_hi; i += 1024) {
        int2 rc = ebuck[i];
        int pos = atomicAdd(&cursor[rc.y], 1);
        esrc[pos] = rc.x;
    }
}

// ---------------- weight conversion: fp32 -> f16 hi/lo in MFMA-frag order ----------------
__global__ __launch_bounds__(256) void k_wconv(const float* __restrict__ w, f16* __restrict__ whi,
                                               f16* __restrict__ wlo) {
    int fi = blockIdx.x * 256 + threadIdx.x;   // 0..16383
    int j  = fi & 7;
    int l  = (fi >> 3) & 63;
    int ks = (fi >> 9) & 3;
    int ct = fi >> 11;
    int k = ks * 32 + (l >> 4) * 8 + j;
    int c = ct * 16 + (l & 15);
    float x = w[k * 128 + c];
    f16 hi = (f16)x;
    f16 lo = (f16)(x - (float)hi);
    whi[fi] = hi;
    wlo[fi] = lo;
}

// ---------------- GEMM via fp16-split MFMA: A[r] = f16(dinv[r] * (in[r] @ W + b)) ----------------
// fp32 input, fp16 output (aggregation input). Math in fp32-accumulating MFMA.
__global__ __launch_bounds__(256) void k_gemm_mfma(const float* __restrict__ in, const f16* __restrict__ whi,
                                                   const f16* __restrict__ wlo, const float* __restrict__ bias,
                                                   const float* __restrict__ dinv, f16* __restrict__ out, int n) {
    int lane = threadIdx.x & 63;
    int wid  = threadIdx.x >> 6;
    int wr = wid >> 1, wc = wid & 1;
    int rbase = blockIdx.x * 64 + wr * 32;
    int rowA = lane & 15;
    int kg   = lane >> 4;

    f32x4 acc[2][4];
    #pragma unroll
    for (int i = 0; i < 2; i++)
        #pragma unroll
        for (int j = 0; j < 4; j++) acc[i][j] = (f32x4){0.f, 0.f, 0.f, 0.f};

    #pragma unroll
    for (int ks = 0; ks < 4; ks++) {
        f16x8 ah[2], al[2];
        #pragma unroll
        for (int rt = 0; rt < 2; rt++) {
            int r = rbase + rt * 16 + rowA;
            int k0 = ks * 32 + kg * 8;
            float4 x0 = make_float4(0.f, 0.f, 0.f, 0.f), x1 = x0;
            if (r < n) {
                const float4* p = (const float4*)(in + (size_t)r * 128 + k0);
                x0 = p[0];
                x1 = p[1];
            }
            float xs[8] = {x0.x, x0.y, x0.z, x0.w, x1.x, x1.y, x1.z, x1.w};
            #pragma unroll
            for (int j = 0; j < 8; j++) {
                f16 h = (f16)xs[j];
                ah[rt][j] = h;
                al[rt][j] = (f16)(xs[j] - (float)h);
            }
        }
        f16x8 bh[4], bl[4];
        #pragma unroll
        for (int ct = 0; ct < 4; ct++) {
            int g = ((wc * 4 + ct) * 4 + ks);
            size_t idx = (size_t)(g * 64 + lane) * 8;
            bh[ct] = *(const f16x8*)(whi + idx);
            bl[ct] = *(const f16x8*)(wlo + idx);
        }
        #pragma unroll
        for (int rt = 0; rt < 2; rt++)
            #pragma unroll
            for (int ct = 0; ct < 4; ct++) {
                acc[rt][ct] = __builtin_amdgcn_mfma_f32_16x16x32_f16(al[rt], bh[ct], acc[rt][ct], 0, 0, 0);
                acc[rt][ct] = __builtin_amdgcn_mfma_f32_16x16x32_f16(ah[rt], bl[ct], acc[rt][ct], 0, 0, 0);
                acc[rt][ct] = __builtin_amdgcn_mfma_f32_16x16x32_f16(ah[rt], bh[ct], acc[rt][ct], 0, 0, 0);
            }
    }

    int cl = lane & 15;
    int rq = lane >> 4;
    #pragma unroll
    for (int rt = 0; rt < 2; rt++) {
        #pragma unroll
        for (int ct = 0; ct < 4; ct++) {
            int c = wc * 64 + ct * 16 + cl;
            float bv = bias[c];
            #pragma unroll
            for (int reg = 0; reg < 4; reg++) {
                int r = rbase + rt * 16 + rq * 4 + reg;
                if (r < n) {
                    float dv = dinv[r];
                    out[(size_t)r * 128 + c] = (f16)(dv * (acc[rt][ct][reg] + bv));
                }
            }
        }
    }
}

// ---------------- Aggregation: B[v] = relu(dinv[v] * (A[v] + sum_{src} A[src])) ----------------
// A is fp16 (half2 per lane, 256 B/row); accumulate fp32; B fp32.
__global__ __launch_bounds__(256) void k_agg(const f16* __restrict__ A, const int* __restrict__ colptr,
                                             const int* __restrict__ esrc, const float* __restrict__ dinv,
                                             float* __restrict__ B, int n) {
    int lane = threadIdx.x & 63;
    int v = blockIdx.x * 4 + (threadIdx.x >> 6);
    if (v >= n) return;
    const f16x2* __restrict__ A2 = (const f16x2*)A;
    int p0 = colptr[v], p1 = colptr[v + 1];
    f16x2 sv = A2[(size_t)v * 64 + lane];       // self loop
    float accx = (float)sv.x, accy = (float)sv.y;
    int p = p0;
    for (; p + 8 <= p1; p += 8) {
        int s0 = esrc[p];
        int s1 = esrc[p + 1];
        int s2 = esrc[p + 2];
        int s3 = esrc[p + 3];
        int s4 = esrc[p + 4];
        int s5 = esrc[p + 5];
        int s6 = esrc[p + 6];
        int s7 = esrc[p + 7];
        f16x2 v0 = A2[(size_t)s0 * 64 + lane];
        f16x2 v1 = A2[(size_t)s1 * 64 + lane];
        f16x2 v2 = A2[(size_t)s2 * 64 + lane];
        f16x2 v3 = A2[(size_t)s3 * 64 + lane];
        f16x2 v4 = A2[(size_t)s4 * 64 + lane];
        f16x2 v5 = A2[(size_t)s5 * 64 + lane];
        f16x2 v6 = A2[(size_t)s6 * 64 + lane];
        f16x2 v7 = A2[(size_t)s7 * 64 + lane];
        accx += (float)v0.x; accy += (float)v0.y;
        accx += (float)v1.x; accy += (float)v1.y;
        accx += (float)v2.x; accy += (float)v2.y;
        accx += (float)v3.x; accy += (float)v3.y;
        accx += (float)v4.x; accy += (float)v4.y;
        accx += (float)v5.x; accy += (float)v5.y;
        accx += (float)v6.x; accy += (float)v6.y;
        accx += (float)v7.x; accy += (float)v7.y;
    }
    for (; p < p1; ++p) {
        int s = esrc[p];
        f16x2 vv = A2[(size_t)s * 64 + lane];
        accx += (float)vv.x; accy += (float)vv.y;
    }
    float d = dinv[v];
    float ox = fmaxf(d * accx, 0.f);
    float oy = fmaxf(d * accy, 0.f);
    ((float2*)B)[(size_t)v * 64 + lane] = make_float2(ox, oy);
}

// ---------------- Pooling (batch is sorted) ----------------
__global__ __launch_bounds__(128) void k_pool(const float* __restrict__ B, const int* __restrict__ batch,
                                              float* __restrict__ gsum, int* __restrict__ gcnt, int n) {
    int c = threadIdx.x;
    int base = blockIdx.x * 64;
    if (base >= n) return;
    int end = min(base + 64, n);
    int curg = batch[base];
    float acc = 0.f;
    int cnt = 0;
    for (int i = base; i < end; i++) {
        int g = batch[i];
        if (g != curg) {
            atomicAdd(&gsum[curg * 128 + c], acc);
            if (c == 0) atomicAdd(&gcnt[curg], cnt);
            acc = 0.f; cnt = 0; curg = g;
        }
        acc += B[i * 128 + c];
        cnt++;
    }
    atomicAdd(&gsum[curg * 128 + c], acc);
    if (c == 0) atomicAdd(&gcnt[curg], cnt);
}

// ---------------- Head ----------------
__global__ __launch_bounds__(128) void k_head(const float* __restrict__ gsum, const int* __restrict__ gcnt,
                                              const float* __restrict__ hw1, const float* __restrict__ hb1,
                                              const float* __restrict__ hw2, const float* __restrict__ hb2,
                                              float* __restrict__ out) {
    __shared__ float mean[128];
    __shared__ float red[128];
    int g = blockIdx.x;
    int c = threadIdx.x;
    float cntf = fmaxf((float)gcnt[g], 1.0f);
    mean[c] = gsum[g * 128 + c] / cntf;
    __syncthreads();
    float h = hb1[c];
    for (int k = 0; k < 128; k++) h = fmaf(mean[k], hw1[k * 128 + c], h);
    h = fmaxf(h, 0.f);
    red[c] = h * hw2[c];
    __syncthreads();
    for (int s = 64; s > 0; s >>= 1) {
        if (c < s) red[c] += red[c + s];
        __syncthreads();
    }
    if (c == 0) out[g] = red[0] + hb2[0];
}

// ---------------- launch ----------------
extern "C" void kernel_launch(void* const* d_in, const int* in_sizes, int n_in,
                              void* d_out, int out_size, void* d_ws, size_t ws_size,
                              hipStream_t stream) {
    const float* x   = (const float*)d_in[0];
    const int*  edge = (const int*)d_in[1];
    const int*  batch= (const int*)d_in[2];
    const float* w1  = (const float*)d_in[3];
    const float* b1  = (const float*)d_in[4];
    const float* w2  = (const float*)d_in[5];
    const float* b2  = (const float*)d_in[6];
    const float* w3  = (const float*)d_in[7];
    const float* b3  = (const float*)d_in[8];
    const float* hw1 = (const float*)d_in[9];
    const float* hb1 = (const float*)d_in[10];
    const float* hw2 = (const float*)d_in[11];
    const float* hb2 = (const float*)d_in[12];
    float* out = (float*)d_out;

    const int n = in_sizes[0] / 128;
    const int e = in_sizes[1] / 2;
    const int* row = edge;
    const int* col = edge + e;

    char* wsb = (char*)d_ws;
    size_t off = 0;
    auto alloc = [&](size_t bytes) -> void* {
        void* p = wsb + off;
        off = (off + bytes + 511) & ~size_t(511);
        return p;
    };
    f16*   A      = (f16*)  alloc((size_t)n * 128 * 2);   // fp16 aggregation input
    float* Bb     = (float*)alloc((size_t)n * 128 * 4);
    float* dinv   = (float*)alloc((size_t)n * 4);
    int*   cnt    = (int*)  alloc((size_t)n * 4);
    int*   colptr = (int*)  alloc((size_t)(n + 1) * 4);
    int*   cursor = (int*)  alloc((size_t)n * 4);
    int*   bsum   = (int*)  alloc(512);
    int*   boff   = (int*)  alloc(512);
    int*   bcur   = (int*)  alloc(1024);
    int*   esrc   = (int*)  alloc((size_t)e * 4);
    float* gsum   = (float*)alloc(64 * 128 * 4);
    int*   gcnt   = (int*)  alloc(64 * 4);
    f16*   whi    = (f16*)  alloc(3 * 16384 * 2);
    f16*   wlo    = (f16*)  alloc(3 * 16384 * 2);
    // ebuck aliases Bb: only live between k_part and k_fill2, before the first k_agg writes Bb
    int2*  ebuck  = (int2*)Bb;

    hipMemsetAsync(cnt,  0, (size_t)n * 4, stream);
    hipMemsetAsync(gsum, 0, 64 * 128 * 4, stream);
    hipMemsetAsync(gcnt, 0, 64 * 4, stream);

    k_wconv<<<64, 256, 0, stream>>>(w1, whi,             wlo);
    k_wconv<<<64, 256, 0, stream>>>(w2, whi + 16384,     wlo + 16384);
    k_wconv<<<64, 256, 0, stream>>>(w3, whi + 2 * 16384, wlo + 2 * 16384);

    k_hist<<<(e + 255) / 256, 256, 0, stream>>>(col, cnt, e);
    k_dinv<<<(n + 255) / 256, 256, 0, stream>>>(cnt, dinv, n);
    int nb = (n + 1023) / 1024;
    k_scan1<<<nb, 256, 0, stream>>>(cnt, colptr, bsum, n);
    k_scan2<<<1, 128, 0, stream>>>(bsum, boff, nb);
    k_scan3<<<(n + 1 + 255) / 256, 256, 0, stream>>>(colptr, boff, cursor, n);
    k_binit<<<1, 256, 0, stream>>>(colptr, bcur, n);
    k_part<<<(e + 4095) / 4096, 256, 0, stream>>>(row, col, bcur, ebuck, e);
    int nbk = (n + (1 << BSH) - 1) >> BSH;
    k_fill2<<<nbk * 4, 256, 0, stream>>>(ebuck, colptr, cursor, esrc, n);

    int gb = (n + 63) / 64;
    k_gemm_mfma<<<gb, 256, 0, stream>>>(x,  whi,             wlo,             b1, dinv, A, n);
    k_agg <<<(n + 3) / 4, 256, 0, stream>>>(A, colptr, esrc, dinv, Bb, n);
    k_gemm_mfma<<<gb, 256, 0, stream>>>(Bb, whi + 16384,     wlo + 16384,     b2, dinv, A, n);
    k_agg <<<(n + 3) / 4, 256, 0, stream>>>(A, colptr, esrc, dinv, Bb, n);
    k_gemm_mfma<<<gb, 256, 0, stream>>>(Bb, whi + 2 * 16384, wlo + 2 * 16384, b3, dinv, A, n);
    k_agg <<<(n + 3) / 4, 256, 0, stream>>>(A, colptr, esrc, dinv, Bb, n);

    k_pool<<<(n + 63) / 64, 128, 0, stream>>>(Bb, batch, gsum, gcnt, n);
    k_head<<<64, 128, 0, stream>>>(gsum, gcnt, hw1, hb1, hw2, hb2, out);
}

// Round 7
// 497.550 us; speedup vs baseline: 2.0435x; 1.0424x over previous
//
#include <hip/hip_runtime.h>

typedef _Float16 f16;
typedef __attribute__((ext_vector_type(2))) _Float16 f16x2;
typedef __attribute__((ext_vector_type(8))) _Float16 f16x8;
typedef __attribute__((ext_vector_type(4))) float f32x4;

#define BSH 9   // 512 nodes per bucket

// ---------------- CSR build ----------------

__global__ __launch_bounds__(256) void k_hist(const int* __restrict__ col, int* __restrict__ cnt, int e) {
    int i = blockIdx.x * 256 + threadIdx.x;
    if (i < e) atomicAdd(&cnt[col[i]], 1);
}

__global__ __launch_bounds__(256) void k_dinv(const int* __restrict__ cnt, float* __restrict__ dinv, int n) {
    int i = blockIdx.x * 256 + threadIdx.x;
    if (i < n) dinv[i] = rsqrtf((float)(cnt[i] + 1));  // +1 self loop
}

// block-level inclusive scan of 1024 elements (256 thr x 4)
__global__ __launch_bounds__(256) void k_scan1(const int* __restrict__ cnt, int* __restrict__ colptr,
                                               int* __restrict__ bsum, int n) {
    __shared__ int lds[256];
    int t = threadIdx.x;
    int base = blockIdx.x * 1024;
    int idx = base + t * 4;
    int4 v = make_int4(0, 0, 0, 0);
    if (idx + 3 < n) {
        v = *(const int4*)(cnt + idx);
    } else {
        if (idx     < n) v.x = cnt[idx];
        if (idx + 1 < n) v.y = cnt[idx + 1];
        if (idx + 2 < n) v.z = cnt[idx + 2];
        if (idx + 3 < n) v.w = cnt[idx + 3];
    }
    int s1 = v.x, s2 = s1 + v.y, s3 = s2 + v.z, s4 = s3 + v.w;
    lds[t] = s4;
    __syncthreads();
    for (int off = 1; off < 256; off <<= 1) {
        int mine = lds[t];
        int add  = (t >= off) ? lds[t - off] : 0;
        __syncthreads();
        lds[t] = mine + add;
        __syncthreads();
    }
    int incl = lds[t];
    int excl = incl - s4;
    if (t == 255) bsum[blockIdx.x] = incl;
    if (idx     < n) colptr[idx + 1] = excl + s1;
    if (idx + 1 < n) colptr[idx + 2] = excl + s2;
    if (idx + 2 < n) colptr[idx + 3] = excl + s3;
    if (idx + 3 < n) colptr[idx + 4] = excl + s4;
}

__global__ __launch_bounds__(128) void k_scan2(const int* __restrict__ bsum, int* __restrict__ boff, int nb) {
    __shared__ int lds[128];
    int t = threadIdx.x;
    int v = (t < nb) ? bsum[t] : 0;
    lds[t] = v;
    __syncthreads();
    for (int off = 1; off < 128; off <<= 1) {
        int mine = lds[t];
        int add  = (t >= off) ? lds[t - off] : 0;
        __syncthreads();
        lds[t] = mine + add;
        __syncthreads();
    }
    if (t < nb) boff[t] = lds[t] - v;  // exclusive
}

__global__ __launch_bounds__(256) void k_scan3(int* __restrict__ colptr, const int* __restrict__ boff,
                                               int* __restrict__ cursor, int n) {
    int j = blockIdx.x * 256 + threadIdx.x;
    if (j > n) return;
    int val;
    if (j == 0) {
        val = 0;
        colptr[0] = 0;
    } else {
        val = colptr[j] + boff[(j - 1) >> 10];
        colptr[j] = val;
    }
    if (j < n) cursor[j] = val;
}

// bucket cursors: bcur[b] = colptr[min(b<<BSH, n)]
__global__ __launch_bounds__(256) void k_binit(const int* __restrict__ colptr, int* __restrict__ bcur, int n) {
    int t = threadIdx.x;
    int node = min(t << BSH, n);
    bcur[t] = colptr[node];
}

// ---------------- bucket partition: edges -> ebuck grouped by (col >> BSH) ----------------
__global__ __launch_bounds__(256) void k_part(const int* __restrict__ row, const int* __restrict__ col,
                                              int* __restrict__ bcur, int2* __restrict__ ebuck, int e) {
    __shared__ int hist[256];
    __shared__ int excl[256];
    __shared__ int rbase[256];
    __shared__ int2 stage[4096];
    int t = threadIdx.x;
    int wgbase = blockIdx.x * 4096;
    int total = min(4096, e - wgbase);

    hist[t] = 0;
    __syncthreads();

    int2 myrc[16];
    int  myrank[16];
    #pragma unroll
    for (int k = 0; k < 16; k++) {
        int i = wgbase + k * 256 + t;
        int2 rc = make_int2(0, 0);
        int rnk = 0;
        if (i < e) {
            rc.x = row[i];
            rc.y = col[i];
            rnk = atomicAdd(&hist[rc.y >> BSH], 1);
        }
        myrc[k] = rc;
        myrank[k] = rnk;
    }
    __syncthreads();

    excl[t] = hist[t];
    __syncthreads();
    for (int off = 1; off < 256; off <<= 1) {
        int mine = excl[t];
        int add  = (t >= off) ? excl[t - off] : 0;
        __syncthreads();
        excl[t] = mine + add;
        __syncthreads();
    }
    excl[t] -= hist[t];
    rbase[t] = (hist[t] > 0) ? atomicAdd(&bcur[t], hist[t]) : 0;
    __syncthreads();

    #pragma unroll
    for (int k = 0; k < 16; k++) {
        int i = wgbase + k * 256 + t;
        if (i < e) stage[excl[myrc[k].y >> BSH] + myrank[k]] = myrc[k];
    }
    __syncthreads();

    for (int j = t; j < total; j += 256) {
        int2 rc = stage[j];
        int b = rc.y >> BSH;
        ebuck[rbase[b] + (j - excl[b])] = rc;
    }
}

// ---------------- fill esrc from bucketed edges ----------------
__global__ __launch_bounds__(256) void k_fill2(const int2* __restrict__ ebuck, const int* __restrict__ colptr,
                                               int* __restrict__ cursor, int* __restrict__ esrc, int n) {
    int b = blockIdx.x >> 2;
    int sub = blockIdx.x & 3;
    int lo_node = b << BSH;
    int hi_node = min((b + 1) << BSH, n);
    if (lo_node >= n) return;
    int e_lo = colptr[lo_node], e_hi = colptr[hi_node];
    for (int i = e_lo + sub * 256 + threadIdx.x; i < e_hi; i += 1024) {
        int2 rc = ebuck[i];
        int pos = atomicAdd(&cursor[rc.y], 1);
        esrc[pos] = rc.x;
    }
}

// ---------------- weight conversion: fp32 -> f16 hi/lo in MFMA-frag order ----------------
__global__ __launch_bounds__(256) void k_wconv(const float* __restrict__ w, f16* __restrict__ whi,
                                               f16* __restrict__ wlo) {
    int fi = blockIdx.x * 256 + threadIdx.x;   // 0..16383
    int j  = fi & 7;
    int l  = (fi >> 3) & 63;
    int ks = (fi >> 9) & 3;
    int ct = fi >> 11;
    int k = ks * 32 + (l >> 4) * 8 + j;
    int c = ct * 16 + (l & 15);
    float x = w[k * 128 + c];
    f16 hi = (f16)x;
    f16 lo = (f16)(x - (float)hi);
    whi[fi] = hi;
    wlo[fi] = lo;
}

// ---------------- GEMM (fp32 input, layer 1): A[r] = f16(dinv[r] * (in[r] @ W + b)) ----------------
__global__ __launch_bounds__(256) void k_gemm_f32in(const float* __restrict__ in, const f16* __restrict__ whi,
                                                    const f16* __restrict__ wlo, const float* __restrict__ bias,
                                                    const float* __restrict__ dinv, f16* __restrict__ out, int n) {
    int lane = threadIdx.x & 63;
    int wid  = threadIdx.x >> 6;
    int wr = wid >> 1, wc = wid & 1;
    int rbase = blockIdx.x * 64 + wr * 32;
    int rowA = lane & 15;
    int kg   = lane >> 4;

    f32x4 acc[2][4];
    #pragma unroll
    for (int i = 0; i < 2; i++)
        #pragma unroll
        for (int j = 0; j < 4; j++) acc[i][j] = (f32x4){0.f, 0.f, 0.f, 0.f};

    #pragma unroll
    for (int ks = 0; ks < 4; ks++) {
        f16x8 ah[2], al[2];
        #pragma unroll
        for (int rt = 0; rt < 2; rt++) {
            int r = rbase + rt * 16 + rowA;
            int k0 = ks * 32 + kg * 8;
            float4 x0 = make_float4(0.f, 0.f, 0.f, 0.f), x1 = x0;
            if (r < n) {
                const float4* p = (const float4*)(in + (size_t)r * 128 + k0);
                x0 = p[0];
                x1 = p[1];
            }
            float xs[8] = {x0.x, x0.y, x0.z, x0.w, x1.x, x1.y, x1.z, x1.w};
            #pragma unroll
            for (int j = 0; j < 8; j++) {
                f16 h = (f16)xs[j];
                ah[rt][j] = h;
                al[rt][j] = (f16)(xs[j] - (float)h);
            }
        }
        f16x8 bh[4], bl[4];
        #pragma unroll
        for (int ct = 0; ct < 4; ct++) {
            int g = ((wc * 4 + ct) * 4 + ks);
            size_t idx = (size_t)(g * 64 + lane) * 8;
            bh[ct] = *(const f16x8*)(whi + idx);
            bl[ct] = *(const f16x8*)(wlo + idx);
        }
        #pragma unroll
        for (int rt = 0; rt < 2; rt++)
            #pragma unroll
            for (int ct = 0; ct < 4; ct++) {
                acc[rt][ct] = __builtin_amdgcn_mfma_f32_16x16x32_f16(al[rt], bh[ct], acc[rt][ct], 0, 0, 0);
                acc[rt][ct] = __builtin_amdgcn_mfma_f32_16x16x32_f16(ah[rt], bl[ct], acc[rt][ct], 0, 0, 0);
                acc[rt][ct] = __builtin_amdgcn_mfma_f32_16x16x32_f16(ah[rt], bh[ct], acc[rt][ct], 0, 0, 0);
            }
    }

    int cl = lane & 15;
    int rq = lane >> 4;
    #pragma unroll
    for (int rt = 0; rt < 2; rt++) {
        #pragma unroll
        for (int ct = 0; ct < 4; ct++) {
            int c = wc * 64 + ct * 16 + cl;
            float bv = bias[c];
            #pragma unroll
            for (int reg = 0; reg < 4; reg++) {
                int r = rbase + rt * 16 + rq * 4 + reg;
                if (r < n) {
                    float dv = dinv[r];
                    out[(size_t)r * 128 + c] = (f16)(dv * (acc[rt][ct][reg] + bv));
                }
            }
        }
    }
}

// ---------------- GEMM (fp16 input, layers 2,3): A[r] = f16(dinv[r] * (in[r] @ W + b)) ----------------
// Input rows are exact fp16 -> no input split; 2 MFMAs per tile (Ah*Bl + Ah*Bh).
__global__ __launch_bounds__(256) void k_gemm_f16in(const f16* __restrict__ in, const f16* __restrict__ whi,
                                                    const f16* __restrict__ wlo, const float* __restrict__ bias,
                                                    const float* __restrict__ dinv, f16* __restrict__ out, int n) {
    int lane = threadIdx.x & 63;
    int wid  = threadIdx.x >> 6;
    int wr = wid >> 1, wc = wid & 1;
    int rbase = blockIdx.x * 64 + wr * 32;
    int rowA = lane & 15;
    int kg   = lane >> 4;

    f32x4 acc[2][4];
    #pragma unroll
    for (int i = 0; i < 2; i++)
        #pragma unroll
        for (int j = 0; j < 4; j++) acc[i][j] = (f32x4){0.f, 0.f, 0.f, 0.f};

    #pragma unroll
    for (int ks = 0; ks < 4; ks++) {
        f16x8 ah[2];
        #pragma unroll
        for (int rt = 0; rt < 2; rt++) {
            int r = rbase + rt * 16 + rowA;
            int k0 = ks * 32 + kg * 8;
            f16x8 v = {};
            if (r < n) v = *(const f16x8*)(in + (size_t)r * 128 + k0);
            ah[rt] = v;
        }
        f16x8 bh[4], bl[4];
        #pragma unroll
        for (int ct = 0; ct < 4; ct++) {
            int g = ((wc * 4 + ct) * 4 + ks);
            size_t idx = (size_t)(g * 64 + lane) * 8;
            bh[ct] = *(const f16x8*)(whi + idx);
            bl[ct] = *(const f16x8*)(wlo + idx);
        }
        #pragma unroll
        for (int rt = 0; rt < 2; rt++)
            #pragma unroll
            for (int ct = 0; ct < 4; ct++) {
                acc[rt][ct] = __builtin_amdgcn_mfma_f32_16x16x32_f16(ah[rt], bl[ct], acc[rt][ct], 0, 0, 0);
                acc[rt][ct] = __builtin_amdgcn_mfma_f32_16x16x32_f16(ah[rt], bh[ct], acc[rt][ct], 0, 0, 0);
            }
    }

    int cl = lane & 15;
    int rq = lane >> 4;
    #pragma unroll
    for (int rt = 0; rt < 2; rt++) {
        #pragma unroll
        for (int ct = 0; ct < 4; ct++) {
            int c = wc * 64 + ct * 16 + cl;
            float bv = bias[c];
            #pragma unroll
            for (int reg = 0; reg < 4; reg++) {
                int r = rbase + rt * 16 + rq * 4 + reg;
                if (r < n) {
                    float dv = dinv[r];
                    out[(size_t)r * 128 + c] = (f16)(dv * (acc[rt][ct][reg] + bv));
                }
            }
        }
    }
}

// ---------------- Aggregation: B[v] = f16(relu(dinv[v] * (A[v] + sum_{src} A[src]))) ----------------
// A fp16, accumulate fp32, B fp16.
__global__ __launch_bounds__(256) void k_agg(const f16* __restrict__ A, const int* __restrict__ colptr,
                                             const int* __restrict__ esrc, const float* __restrict__ dinv,
                                             f16* __restrict__ B, int n) {
    int lane = threadIdx.x & 63;
    int v = blockIdx.x * 4 + (threadIdx.x >> 6);
    if (v >= n) return;
    const f16x2* __restrict__ A2 = (const f16x2*)A;
    int p0 = colptr[v], p1 = colptr[v + 1];
    f16x2 sv = A2[(size_t)v * 64 + lane];       // self loop
    float accx = (float)sv.x, accy = (float)sv.y;
    int p = p0;
    for (; p + 8 <= p1; p += 8) {
        int s0 = esrc[p];
        int s1 = esrc[p + 1];
        int s2 = esrc[p + 2];
        int s3 = esrc[p + 3];
        int s4 = esrc[p + 4];
        int s5 = esrc[p + 5];
        int s6 = esrc[p + 6];
        int s7 = esrc[p + 7];
        f16x2 v0 = A2[(size_t)s0 * 64 + lane];
        f16x2 v1 = A2[(size_t)s1 * 64 + lane];
        f16x2 v2 = A2[(size_t)s2 * 64 + lane];
        f16x2 v3 = A2[(size_t)s3 * 64 + lane];
        f16x2 v4 = A2[(size_t)s4 * 64 + lane];
        f16x2 v5 = A2[(size_t)s5 * 64 + lane];
        f16x2 v6 = A2[(size_t)s6 * 64 + lane];
        f16x2 v7 = A2[(size_t)s7 * 64 + lane];
        accx += (float)v0.x; accy += (float)v0.y;
        accx += (float)v1.x; accy += (float)v1.y;
        accx += (float)v2.x; accy += (float)v2.y;
        accx += (float)v3.x; accy += (float)v3.y;
        accx += (float)v4.x; accy += (float)v4.y;
        accx += (float)v5.x; accy += (float)v5.y;
        accx += (float)v6.x; accy += (float)v6.y;
        accx += (float)v7.x; accy += (float)v7.y;
    }
    for (; p < p1; ++p) {
        int s = esrc[p];
        f16x2 vv = A2[(size_t)s * 64 + lane];
        accx += (float)vv.x; accy += (float)vv.y;
    }
    float d = dinv[v];
    f16x2 o;
    o.x = (f16)fmaxf(d * accx, 0.f);
    o.y = (f16)fmaxf(d * accy, 0.f);
    ((f16x2*)B)[(size_t)v * 64 + lane] = o;
}

// ---------------- Pooling (batch is sorted), B fp16 ----------------
__global__ __launch_bounds__(128) void k_pool(const f16* __restrict__ B, const int* __restrict__ batch,
                                              float* __restrict__ gsum, int* __restrict__ gcnt, int n) {
    int c = threadIdx.x;
    int base = blockIdx.x * 64;
    if (base >= n) return;
    int end = min(base + 64, n);
    int curg = batch[base];
    float acc = 0.f;
    int cnt = 0;
    for (int i = base; i < end; i++) {
        int g = batch[i];
        if (g != curg) {
            atomicAdd(&gsum[curg * 128 + c], acc);
            if (c == 0) atomicAdd(&gcnt[curg], cnt);
            acc = 0.f; cnt = 0; curg = g;
        }
        acc += (float)B[(size_t)i * 128 + c];
        cnt++;
    }
    atomicAdd(&gsum[curg * 128 + c], acc);
    if (c == 0) atomicAdd(&gcnt[curg], cnt);
}

// ---------------- Head ----------------
__global__ __launch_bounds__(128) void k_head(const float* __restrict__ gsum, const int* __restrict__ gcnt,
                                              const float* __restrict__ hw1, const float* __restrict__ hb1,
                                              const float* __restrict__ hw2, const float* __restrict__ hb2,
                                              float* __restrict__ out) {
    __shared__ float mean[128];
    __shared__ float red[128];
    int g = blockIdx.x;
    int c = threadIdx.x;
    float cntf = fmaxf((float)gcnt[g], 1.0f);
    mean[c] = gsum[g * 128 + c] / cntf;
    __syncthreads();
    float h = hb1[c];
    for (int k = 0; k < 128; k++) h = fmaf(mean[k], hw1[k * 128 + c], h);
    h = fmaxf(h, 0.f);
    red[c] = h * hw2[c];
    __syncthreads();
    for (int s = 64; s > 0; s >>= 1) {
        if (c < s) red[c] += red[c + s];
        __syncthreads();
    }
    if (c == 0) out[g] = red[0] + hb2[0];
}

// ---------------- launch ----------------
extern "C" void kernel_launch(void* const* d_in, const int* in_sizes, int n_in,
                              void* d_out, int out_size, void* d_ws, size_t ws_size,
                              hipStream_t stream) {
    const float* x   = (const float*)d_in[0];
    const int*  edge = (const int*)d_in[1];
    const int*  batch= (const int*)d_in[2];
    const float* w1  = (const float*)d_in[3];
    const float* b1  = (const float*)d_in[4];
    const float* w2  = (const float*)d_in[5];
    const float* b2  = (const float*)d_in[6];
    const float* w3  = (const float*)d_in[7];
    const float* b3  = (const float*)d_in[8];
    const float* hw1 = (const float*)d_in[9];
    const float* hb1 = (const float*)d_in[10];
    const float* hw2 = (const float*)d_in[11];
    const float* hb2 = (const float*)d_in[12];
    float* out = (float*)d_out;

    const int n = in_sizes[0] / 128;
    const int e = in_sizes[1] / 2;
    const int* row = edge;
    const int* col = edge + e;

    char* wsb = (char*)d_ws;
    size_t off = 0;
    auto alloc = [&](size_t bytes) -> void* {
        void* p = wsb + off;
        off = (off + bytes + 511) & ~size_t(511);
        return p;
    };
    f16*   A      = (f16*)  alloc((size_t)n * 128 * 2);   // fp16 activations (gemm out)
    f16*   Bb     = (f16*)  alloc((size_t)n * 128 * 2);   // fp16 activations (agg out)
    int2*  ebuck  = (int2*) alloc((size_t)e * 8);         // bucketed edges (standalone now)
    float* dinv   = (float*)alloc((size_t)n * 4);
    int*   cnt    = (int*)  alloc((size_t)n * 4);
    int*   colptr = (int*)  alloc((size_t)(n + 1) * 4);
    int*   cursor = (int*)  alloc((size_t)n * 4);
    int*   bsum   = (int*)  alloc(512);
    int*   boff   = (int*)  alloc(512);
    int*   bcur   = (int*)  alloc(1024);
    int*   esrc   = (int*)  alloc((size_t)e * 4);
    float* gsum   = (float*)alloc(64 * 128 * 4);
    int*   gcnt   = (int*)  alloc(64 * 4);
    f16*   whi    = (f16*)  alloc(3 * 16384 * 2);
    f16*   wlo    = (f16*)  alloc(3 * 16384 * 2);

    hipMemsetAsync(cnt,  0, (size_t)n * 4, stream);
    hipMemsetAsync(gsum, 0, 64 * 128 * 4, stream);
    hipMemsetAsync(gcnt, 0, 64 * 4, stream);

    k_wconv<<<64, 256, 0, stream>>>(w1, whi,             wlo);
    k_wconv<<<64, 256, 0, stream>>>(w2, whi + 16384,     wlo + 16384);
    k_wconv<<<64, 256, 0, stream>>>(w3, whi + 2 * 16384, wlo + 2 * 16384);

    k_hist<<<(e + 255) / 256, 256, 0, stream>>>(col, cnt, e);
    k_dinv<<<(n + 255) / 256, 256, 0, stream>>>(cnt, dinv, n);
    int nb = (n + 1023) / 1024;
    k_scan1<<<nb, 256, 0, stream>>>(cnt, colptr, bsum, n);
    k_scan2<<<1, 128, 0, stream>>>(bsum, boff, nb);
    k_scan3<<<(n + 1 + 255) / 256, 256, 0, stream>>>(colptr, boff, cursor, n);
    k_binit<<<1, 256, 0, stream>>>(colptr, bcur, n);
    k_part<<<(e + 4095) / 4096, 256, 0, stream>>>(row, col, bcur, ebuck, e);
    int nbk = (n + (1 << BSH) - 1) >> BSH;
    k_fill2<<<nbk * 4, 256, 0, stream>>>(ebuck, colptr, cursor, esrc, n);

    int gb = (n + 63) / 64;
    k_gemm_f32in<<<gb, 256, 0, stream>>>(x,  whi,             wlo,             b1, dinv, A, n);
    k_agg <<<(n + 3) / 4, 256, 0, stream>>>(A, colptr, esrc, dinv, Bb, n);
    k_gemm_f16in<<<gb, 256, 0, stream>>>(Bb, whi + 16384,     wlo + 16384,     b2, dinv, A, n);
    k_agg <<<(n + 3) / 4, 256, 0, stream>>>(A, colptr, esrc, dinv, Bb, n);
    k_gemm_f16in<<<gb, 256, 0, stream>>>(Bb, whi + 2 * 16384, wlo + 2 * 16384, b3, dinv, A, n);
    k_agg <<<(n + 3) / 4, 256, 0, stream>>>(A, colptr, esrc, dinv, Bb, n);

    k_pool<<<(n + 63) / 64, 128, 0, stream>>>(Bb, batch, gsum, gcnt, n);
    k_head<<<64, 128, 0, stream>>>(gsum, gcnt, hw1, hb1, hw2, hb2, out);
}

// Round 8
// 464.007 us; speedup vs baseline: 2.1912x; 1.0723x over previous
//
#include <hip/hip_runtime.h>

typedef _Float16 f16;
typedef __attribute__((ext_vector_type(2))) _Float16 f16x2;
typedef __attribute__((ext_vector_type(8))) _Float16 f16x8;
typedef __attribute__((ext_vector_type(4))) float f32x4;

#define BSH 9   // 512 nodes per bucket

// ---------------- CSR build ----------------

__global__ __launch_bounds__(256) void k_hist(const int* __restrict__ col, int* __restrict__ cnt, int e) {
    int i = blockIdx.x * 256 + threadIdx.x;
    if (i < e) atomicAdd(&cnt[col[i]], 1);
}

__global__ __launch_bounds__(256) void k_dinv(const int* __restrict__ cnt, float* __restrict__ dinv, int n) {
    int i = blockIdx.x * 256 + threadIdx.x;
    if (i < n) dinv[i] = rsqrtf((float)(cnt[i] + 1));  // +1 self loop
}

// block-level inclusive scan of 1024 elements (256 thr x 4)
__global__ __launch_bounds__(256) void k_scan1(const int* __restrict__ cnt, int* __restrict__ colptr,
                                               int* __restrict__ bsum, int n) {
    __shared__ int lds[256];
    int t = threadIdx.x;
    int base = blockIdx.x * 1024;
    int idx = base + t * 4;
    int4 v = make_int4(0, 0, 0, 0);
    if (idx + 3 < n) {
        v = *(const int4*)(cnt + idx);
    } else {
        if (idx     < n) v.x = cnt[idx];
        if (idx + 1 < n) v.y = cnt[idx + 1];
        if (idx + 2 < n) v.z = cnt[idx + 2];
        if (idx + 3 < n) v.w = cnt[idx + 3];
    }
    int s1 = v.x, s2 = s1 + v.y, s3 = s2 + v.z, s4 = s3 + v.w;
    lds[t] = s4;
    __syncthreads();
    for (int off = 1; off < 256; off <<= 1) {
        int mine = lds[t];
        int add  = (t >= off) ? lds[t - off] : 0;
        __syncthreads();
        lds[t] = mine + add;
        __syncthreads();
    }
    int incl = lds[t];
    int excl = incl - s4;
    if (t == 255) bsum[blockIdx.x] = incl;
    if (idx     < n) colptr[idx + 1] = excl + s1;
    if (idx + 1 < n) colptr[idx + 2] = excl + s2;
    if (idx + 2 < n) colptr[idx + 3] = excl + s3;
    if (idx + 3 < n) colptr[idx + 4] = excl + s4;
}

__global__ __launch_bounds__(128) void k_scan2(const int* __restrict__ bsum, int* __restrict__ boff, int nb) {
    __shared__ int lds[128];
    int t = threadIdx.x;
    int v = (t < nb) ? bsum[t] : 0;
    lds[t] = v;
    __syncthreads();
    for (int off = 1; off < 128; off <<= 1) {
        int mine = lds[t];
        int add  = (t >= off) ? lds[t - off] : 0;
        __syncthreads();
        lds[t] = mine + add;
        __syncthreads();
    }
    if (t < nb) boff[t] = lds[t] - v;  // exclusive
}

__global__ __launch_bounds__(256) void k_scan3(int* __restrict__ colptr, const int* __restrict__ boff,
                                               int* __restrict__ cursor, int n) {
    int j = blockIdx.x * 256 + threadIdx.x;
    if (j > n) return;
    int val;
    if (j == 0) {
        val = 0;
        colptr[0] = 0;
    } else {
        val = colptr[j] + boff[(j - 1) >> 10];
        colptr[j] = val;
    }
    if (j < n) cursor[j] = val;
}

// bucket cursors: bcur[b] = colptr[min(b<<BSH, n)]
__global__ __launch_bounds__(256) void k_binit(const int* __restrict__ colptr, int* __restrict__ bcur, int n) {
    int t = threadIdx.x;
    int node = min(t << BSH, n);
    bcur[t] = colptr[node];
}

// ---------------- bucket partition: edges -> ebuck grouped by (col >> BSH) ----------------
__global__ __launch_bounds__(256) void k_part(const int* __restrict__ row, const int* __restrict__ col,
                                              int* __restrict__ bcur, int2* __restrict__ ebuck, int e) {
    __shared__ int hist[256];
    __shared__ int excl[256];
    __shared__ int rbase[256];
    __shared__ int2 stage[4096];
    int t = threadIdx.x;
    int wgbase = blockIdx.x * 4096;
    int total = min(4096, e - wgbase);

    hist[t] = 0;
    __syncthreads();

    int2 myrc[16];
    int  myrank[16];
    #pragma unroll
    for (int k = 0; k < 16; k++) {
        int i = wgbase + k * 256 + t;
        int2 rc = make_int2(0, 0);
        int rnk = 0;
        if (i < e) {
            rc.x = row[i];
            rc.y = col[i];
            rnk = atomicAdd(&hist[rc.y >> BSH], 1);
        }
        myrc[k] = rc;
        myrank[k] = rnk;
    }
    __syncthreads();

    excl[t] = hist[t];
    __syncthreads();
    for (int off = 1; off < 256; off <<= 1) {
        int mine = excl[t];
        int add  = (t >= off) ? excl[t - off] : 0;
        __syncthreads();
        excl[t] = mine + add;
        __syncthreads();
    }
    excl[t] -= hist[t];
    rbase[t] = (hist[t] > 0) ? atomicAdd(&bcur[t], hist[t]) : 0;
    __syncthreads();

    #pragma unroll
    for (int k = 0; k < 16; k++) {
        int i = wgbase + k * 256 + t;
        if (i < e) stage[excl[myrc[k].y >> BSH] + myrank[k]] = myrc[k];
    }
    __syncthreads();

    for (int j = t; j < total; j += 256) {
        int2 rc = stage[j];
        int b = rc.y >> BSH;
        ebuck[rbase[b] + (j - excl[b])] = rc;
    }
}

// ---------------- fill esrc from bucketed edges ----------------
__global__ __launch_bounds__(256) void k_fill2(const int2* __restrict__ ebuck, const int* __restrict__ colptr,
                                               int* __restrict__ cursor, int* __restrict__ esrc, int n) {
    int b = blockIdx.x >> 2;
    int sub = blockIdx.x & 3;
    int lo_node = b << BSH;
    int hi_node = min((b + 1) << BSH, n);
    if (lo_node >= n) return;
    int e_lo = colptr[lo_node], e_hi = colptr[hi_node];
    for (int i = e_lo + sub * 256 + threadIdx.x; i < e_hi; i += 1024) {
        int2 rc = ebuck[i];
        int pos = atomicAdd(&cursor[rc.y], 1);
        esrc[pos] = rc.x;
    }
}

// ---------------- weight conversion: fp32 -> f16 hi/lo in MFMA-frag order ----------------
__global__ __launch_bounds__(256) void k_wconv(const float* __restrict__ w, f16* __restrict__ whi,
                                               f16* __restrict__ wlo) {
    int fi = blockIdx.x * 256 + threadIdx.x;   // 0..16383
    int j  = fi & 7;
    int l  = (fi >> 3) & 63;
    int ks = (fi >> 9) & 3;
    int ct = fi >> 11;
    int k = ks * 32 + (l >> 4) * 8 + j;
    int c = ct * 16 + (l & 15);
    float x = w[k * 128 + c];
    f16 hi = (f16)x;
    f16 lo = (f16)(x - (float)hi);
    whi[fi] = hi;
    wlo[fi] = lo;
}

// ---------------- GEMM (fp32 input, layer 1): A[r] = f16(dinv[r] * (in[r] @ W + b)) ----------------
__global__ __launch_bounds__(256) void k_gemm_f32in(const float* __restrict__ in, const f16* __restrict__ whi,
                                                    const f16* __restrict__ wlo, const float* __restrict__ bias,
                                                    const float* __restrict__ dinv, f16* __restrict__ out, int n) {
    int lane = threadIdx.x & 63;
    int wid  = threadIdx.x >> 6;
    int wr = wid >> 1, wc = wid & 1;
    int rbase = blockIdx.x * 64 + wr * 32;
    int rowA = lane & 15;
    int kg   = lane >> 4;

    f32x4 acc[2][4];
    #pragma unroll
    for (int i = 0; i < 2; i++)
        #pragma unroll
        for (int j = 0; j < 4; j++) acc[i][j] = (f32x4){0.f, 0.f, 0.f, 0.f};

    #pragma unroll
    for (int ks = 0; ks < 4; ks++) {
        f16x8 ah[2], al[2];
        #pragma unroll
        for (int rt = 0; rt < 2; rt++) {
            int r = rbase + rt * 16 + rowA;
            int k0 = ks * 32 + kg * 8;
            float4 x0 = make_float4(0.f, 0.f, 0.f, 0.f), x1 = x0;
            if (r < n) {
                const float4* p = (const float4*)(in + (size_t)r * 128 + k0);
                x0 = p[0];
                x1 = p[1];
            }
            float xs[8] = {x0.x, x0.y, x0.z, x0.w, x1.x, x1.y, x1.z, x1.w};
            #pragma unroll
            for (int j = 0; j < 8; j++) {
                f16 h = (f16)xs[j];
                ah[rt][j] = h;
                al[rt][j] = (f16)(xs[j] - (float)h);
            }
        }
        f16x8 bh[4], bl[4];
        #pragma unroll
        for (int ct = 0; ct < 4; ct++) {
            int g = ((wc * 4 + ct) * 4 + ks);
            size_t idx = (size_t)(g * 64 + lane) * 8;
            bh[ct] = *(const f16x8*)(whi + idx);
            bl[ct] = *(const f16x8*)(wlo + idx);
        }
        #pragma unroll
        for (int rt = 0; rt < 2; rt++)
            #pragma unroll
            for (int ct = 0; ct < 4; ct++) {
                acc[rt][ct] = __builtin_amdgcn_mfma_f32_16x16x32_f16(al[rt], bh[ct], acc[rt][ct], 0, 0, 0);
                acc[rt][ct] = __builtin_amdgcn_mfma_f32_16x16x32_f16(ah[rt], bl[ct], acc[rt][ct], 0, 0, 0);
                acc[rt][ct] = __builtin_amdgcn_mfma_f32_16x16x32_f16(ah[rt], bh[ct], acc[rt][ct], 0, 0, 0);
            }
    }

    int cl = lane & 15;
    int rq = lane >> 4;
    #pragma unroll
    for (int rt = 0; rt < 2; rt++) {
        #pragma unroll
        for (int ct = 0; ct < 4; ct++) {
            int c = wc * 64 + ct * 16 + cl;
            float bv = bias[c];
            #pragma unroll
            for (int reg = 0; reg < 4; reg++) {
                int r = rbase + rt * 16 + rq * 4 + reg;
                if (r < n) {
                    float dv = dinv[r];
                    out[(size_t)r * 128 + c] = (f16)(dv * (acc[rt][ct][reg] + bv));
                }
            }
        }
    }
}

// ---------------- GEMM (fp16 input, layers 2,3) ----------------
__global__ __launch_bounds__(256) void k_gemm_f16in(const f16* __restrict__ in, const f16* __restrict__ whi,
                                                    const f16* __restrict__ wlo, const float* __restrict__ bias,
                                                    const float* __restrict__ dinv, f16* __restrict__ out, int n) {
    int lane = threadIdx.x & 63;
    int wid  = threadIdx.x >> 6;
    int wr = wid >> 1, wc = wid & 1;
    int rbase = blockIdx.x * 64 + wr * 32;
    int rowA = lane & 15;
    int kg   = lane >> 4;

    f32x4 acc[2][4];
    #pragma unroll
    for (int i = 0; i < 2; i++)
        #pragma unroll
        for (int j = 0; j < 4; j++) acc[i][j] = (f32x4){0.f, 0.f, 0.f, 0.f};

    #pragma unroll
    for (int ks = 0; ks < 4; ks++) {
        f16x8 ah[2];
        #pragma unroll
        for (int rt = 0; rt < 2; rt++) {
            int r = rbase + rt * 16 + rowA;
            int k0 = ks * 32 + kg * 8;
            f16x8 v = {};
            if (r < n) v = *(const f16x8*)(in + (size_t)r * 128 + k0);
            ah[rt] = v;
        }
        f16x8 bh[4], bl[4];
        #pragma unroll
        for (int ct = 0; ct < 4; ct++) {
            int g = ((wc * 4 + ct) * 4 + ks);
            size_t idx = (size_t)(g * 64 + lane) * 8;
            bh[ct] = *(const f16x8*)(whi + idx);
            bl[ct] = *(const f16x8*)(wlo + idx);
        }
        #pragma unroll
        for (int rt = 0; rt < 2; rt++)
            #pragma unroll
            for (int ct = 0; ct < 4; ct++) {
                acc[rt][ct] = __builtin_amdgcn_mfma_f32_16x16x32_f16(ah[rt], bl[ct], acc[rt][ct], 0, 0, 0);
                acc[rt][ct] = __builtin_amdgcn_mfma_f32_16x16x32_f16(ah[rt], bh[ct], acc[rt][ct], 0, 0, 0);
            }
    }

    int cl = lane & 15;
    int rq = lane >> 4;
    #pragma unroll
    for (int rt = 0; rt < 2; rt++) {
        #pragma unroll
        for (int ct = 0; ct < 4; ct++) {
            int c = wc * 64 + ct * 16 + cl;
            float bv = bias[c];
            #pragma unroll
            for (int reg = 0; reg < 4; reg++) {
                int r = rbase + rt * 16 + rq * 4 + reg;
                if (r < n) {
                    float dv = dinv[r];
                    out[(size_t)r * 128 + c] = (f16)(dv * (acc[rt][ct][reg] + bv));
                }
            }
        }
    }
}

// ---------------- Aggregation v3: 4 edges per wave-load ----------------
// lane = eg*16 + cs: eg = edge slot (0..3), cs = column segment (8 cols each).
// One f16x8 load per lane gathers 4 edges x 256 B = 1 KB per instruction.
// Self-loop folded in as virtual last edge; invalid slots masked by fma 0.
// Cross-eg reduction via shfl_xor(32), shfl_xor(16).
__global__ __launch_bounds__(256) void k_agg(const f16* __restrict__ A, const int* __restrict__ colptr,
                                             const int* __restrict__ esrc, const float* __restrict__ dinv,
                                             f16* __restrict__ B, int n) {
    int lane = threadIdx.x & 63;
    int v = blockIdx.x * 4 + (threadIdx.x >> 6);
    if (v >= n) return;
    int eg = lane >> 4;
    int cs = lane & 15;
    const f16x8* __restrict__ A8 = (const f16x8*)A;
    int p0 = colptr[v], p1 = colptr[v + 1];
    int total = p1 - p0 + 1;   // neighbors + self

    float acc[8];
    #pragma unroll
    for (int j = 0; j < 8; j++) acc[j] = 0.f;

    for (int base = 0; base < total; base += 8) {
        int q0 = base + eg;
        int q1 = base + 4 + eg;
        bool ok0 = q0 < total, ok1 = q1 < total;
        int s0 = (q0 < total - 1) ? esrc[p0 + q0] : v;
        int s1 = (q1 < total - 1) ? esrc[p0 + q1] : v;
        f16x8 r0 = A8[(size_t)s0 * 16 + cs];
        f16x8 r1 = A8[(size_t)s1 * 16 + cs];
        float m0 = ok0 ? 1.f : 0.f;
        float m1 = ok1 ? 1.f : 0.f;
        #pragma unroll
        for (int j = 0; j < 8; j++) acc[j] = fmaf(m0, (float)r0[j], acc[j]);
        #pragma unroll
        for (int j = 0; j < 8; j++) acc[j] = fmaf(m1, (float)r1[j], acc[j]);
    }

    #pragma unroll
    for (int j = 0; j < 8; j++) {
        acc[j] += __shfl_xor(acc[j], 32, 64);
        acc[j] += __shfl_xor(acc[j], 16, 64);
    }

    if (lane < 16) {
        float d = dinv[v];
        f16x8 o;
        #pragma unroll
        for (int j = 0; j < 8; j++) o[j] = (f16)fmaxf(d * acc[j], 0.f);
        ((f16x8*)B)[(size_t)v * 16 + cs] = o;
    }
}

// ---------------- Pooling (batch is sorted), B fp16 ----------------
__global__ __launch_bounds__(128) void k_pool(const f16* __restrict__ B, const int* __restrict__ batch,
                                              float* __restrict__ gsum, int* __restrict__ gcnt, int n) {
    int c = threadIdx.x;
    int base = blockIdx.x * 64;
    if (base >= n) return;
    int end = min(base + 64, n);
    int curg = batch[base];
    float acc = 0.f;
    int cnt = 0;
    for (int i = base; i < end; i++) {
        int g = batch[i];
        if (g != curg) {
            atomicAdd(&gsum[curg * 128 + c], acc);
            if (c == 0) atomicAdd(&gcnt[curg], cnt);
            acc = 0.f; cnt = 0; curg = g;
        }
        acc += (float)B[(size_t)i * 128 + c];
        cnt++;
    }
    atomicAdd(&gsum[curg * 128 + c], acc);
    if (c == 0) atomicAdd(&gcnt[curg], cnt);
}

// ---------------- Head ----------------
__global__ __launch_bounds__(128) void k_head(const float* __restrict__ gsum, const int* __restrict__ gcnt,
                                              const float* __restrict__ hw1, const float* __restrict__ hb1,
                                              const float* __restrict__ hw2, const float* __restrict__ hb2,
                                              float* __restrict__ out) {
    __shared__ float mean[128];
    __shared__ float red[128];
    int g = blockIdx.x;
    int c = threadIdx.x;
    float cntf = fmaxf((float)gcnt[g], 1.0f);
    mean[c] = gsum[g * 128 + c] / cntf;
    __syncthreads();
    float h = hb1[c];
    for (int k = 0; k < 128; k++) h = fmaf(mean[k], hw1[k * 128 + c], h);
    h = fmaxf(h, 0.f);
    red[c] = h * hw2[c];
    __syncthreads();
    for (int s = 64; s > 0; s >>= 1) {
        if (c < s) red[c] += red[c + s];
        __syncthreads();
    }
    if (c == 0) out[g] = red[0] + hb2[0];
}

// ---------------- launch ----------------
extern "C" void kernel_launch(void* const* d_in, const int* in_sizes, int n_in,
                              void* d_out, int out_size, void* d_ws, size_t ws_size,
                              hipStream_t stream) {
    const float* x   = (const float*)d_in[0];
    const int*  edge = (const int*)d_in[1];
    const int*  batch= (const int*)d_in[2];
    const float* w1  = (const float*)d_in[3];
    const float* b1  = (const float*)d_in[4];
    const float* w2  = (const float*)d_in[5];
    const float* b2  = (const float*)d_in[6];
    const float* w3  = (const float*)d_in[7];
    const float* b3  = (const float*)d_in[8];
    const float* hw1 = (const float*)d_in[9];
    const float* hb1 = (const float*)d_in[10];
    const float* hw2 = (const float*)d_in[11];
    const float* hb2 = (const float*)d_in[12];
    float* out = (float*)d_out;

    const int n = in_sizes[0] / 128;
    const int e = in_sizes[1] / 2;
    const int* row = edge;
    const int* col = edge + e;

    char* wsb = (char*)d_ws;
    size_t off = 0;
    auto alloc = [&](size_t bytes) -> void* {
        void* p = wsb + off;
        off = (off + bytes + 511) & ~size_t(511);
        return p;
    };
    f16*   A      = (f16*)  alloc((size_t)n * 128 * 2);   // fp16 activations (gemm out)
    f16*   Bb     = (f16*)  alloc((size_t)n * 128 * 2);   // fp16 activations (agg out)
    int2*  ebuck  = (int2*) alloc((size_t)e * 8);         // bucketed edges
    float* dinv   = (float*)alloc((size_t)n * 4);
    int*   cnt    = (int*)  alloc((size_t)n * 4);
    int*   colptr = (int*)  alloc((size_t)(n + 1) * 4);
    int*   cursor = (int*)  alloc((size_t)n * 4);
    int*   bsum   = (int*)  alloc(512);
    int*   boff   = (int*)  alloc(512);
    int*   bcur   = (int*)  alloc(1024);
    int*   esrc   = (int*)  alloc((size_t)e * 4);
    float* gsum   = (float*)alloc(64 * 128 * 4);
    int*   gcnt   = (int*)  alloc(64 * 4);
    f16*   whi    = (f16*)  alloc(3 * 16384 * 2);
    f16*   wlo    = (f16*)  alloc(3 * 16384 * 2);

    hipMemsetAsync(cnt,  0, (size_t)n * 4, stream);
    hipMemsetAsync(gsum, 0, 64 * 128 * 4, stream);
    hipMemsetAsync(gcnt, 0, 64 * 4, stream);

    k_wconv<<<64, 256, 0, stream>>>(w1, whi,             wlo);
    k_wconv<<<64, 256, 0, stream>>>(w2, whi + 16384,     wlo + 16384);
    k_wconv<<<64, 256, 0, stream>>>(w3, whi + 2 * 16384, wlo + 2 * 16384);

    k_hist<<<(e + 255) / 256, 256, 0, stream>>>(col, cnt, e);
    k_dinv<<<(n + 255) / 256, 256, 0, stream>>>(cnt, dinv, n);
    int nb = (n + 1023) / 1024;
    k_scan1<<<nb, 256, 0, stream>>>(cnt, colptr, bsum, n);
    k_scan2<<<1, 128, 0, stream>>>(bsum, boff, nb);
    k_scan3<<<(n + 1 + 255) / 256, 256, 0, stream>>>(colptr, boff, cursor, n);
    k_binit<<<1, 256, 0, stream>>>(colptr, bcur, n);
    k_part<<<(e + 4095) / 4096, 256, 0, stream>>>(row, col, bcur, ebuck, e);
    int nbk = (n + (1 << BSH) - 1) >> BSH;
    k_fill2<<<nbk * 4, 256, 0, stream>>>(ebuck, colptr, cursor, esrc, n);

    int gb = (n + 63) / 64;
    k_gemm_f32in<<<gb, 256, 0, stream>>>(x,  whi,             wlo,             b1, dinv, A, n);
    k_agg <<<(n + 3) / 4, 256, 0, stream>>>(A, colptr, esrc, dinv, Bb, n);
    k_gemm_f16in<<<gb, 256, 0, stream>>>(Bb, whi + 16384,     wlo + 16384,     b2, dinv, A, n);
    k_agg <<<(n + 3) / 4, 256, 0, stream>>>(A, colptr, esrc, dinv, Bb, n);
    k_gemm_f16in<<<gb, 256, 0, stream>>>(Bb, whi + 2 * 16384, wlo + 2 * 16384, b3, dinv, A, n);
    k_agg <<<(n + 3) / 4, 256, 0, stream>>>(A, colptr, esrc, dinv, Bb, n);

    k_pool<<<(n + 63) / 64, 128, 0, stream>>>(Bb, batch, gsum, gcnt, n);
    k_head<<<64, 128, 0, stream>>>(gsum, gcnt, hw1, hb1, hw2, hb2, out);
}

// Round 9
// 413.960 us; speedup vs baseline: 2.4562x; 1.1209x over previous
//
#include <hip/hip_runtime.h>

typedef _Float16 f16;
typedef __attribute__((ext_vector_type(2))) _Float16 f16x2;
typedef __attribute__((ext_vector_type(8))) _Float16 f16x8;
typedef __attribute__((ext_vector_type(4))) float f32x4;

#define BSH 9   // 512 nodes per bucket

// ---------------- bucket count: 256-bin histogram of (col >> BSH) ----------------
__global__ __launch_bounds__(256) void k_bcount(const int* __restrict__ col, int* __restrict__ bcnt, int e) {
    __shared__ int h[256];
    int t = threadIdx.x;
    h[t] = 0;
    __syncthreads();
    int i0 = blockIdx.x * 4096;
    int i1 = min(i0 + 4096, e);
    for (int i = i0 + t; i < i1; i += 256) atomicAdd(&h[col[i] >> BSH], 1);
    __syncthreads();
    if (h[t]) atomicAdd(&bcnt[t], h[t]);
}

// ---------------- bucket scan: bbase[257], bcur init; colptr[n]=e ----------------
__global__ __launch_bounds__(256) void k_bscan(const int* __restrict__ bcnt, int* __restrict__ bbase,
                                               int* __restrict__ bcur, int* __restrict__ colptr, int e, int n) {
    __shared__ int s[256];
    int t = threadIdx.x;
    int v = bcnt[t];
    s[t] = v;
    __syncthreads();
    for (int off = 1; off < 256; off <<= 1) {
        int mine = s[t];
        int add  = (t >= off) ? s[t - off] : 0;
        __syncthreads();
        s[t] = mine + add;
        __syncthreads();
    }
    int incl = s[t];
    bbase[t + 1] = incl;
    bcur[t] = incl - v;      // exclusive base
    if (t == 0) {
        bbase[0] = 0;
        colptr[n] = e;
    }
}

// ---------------- bucket partition: edges -> ebuck grouped by (col >> BSH) ----------------
__global__ __launch_bounds__(256) void k_part(const int* __restrict__ row, const int* __restrict__ col,
                                              int* __restrict__ bcur, int2* __restrict__ ebuck, int e) {
    __shared__ int hist[256];
    __shared__ int excl[256];
    __shared__ int rbase[256];
    __shared__ int2 stage[4096];
    int t = threadIdx.x;
    int wgbase = blockIdx.x * 4096;
    int total = min(4096, e - wgbase);

    hist[t] = 0;
    __syncthreads();

    int2 myrc[16];
    int  myrank[16];
    #pragma unroll
    for (int k = 0; k < 16; k++) {
        int i = wgbase + k * 256 + t;
        int2 rc = make_int2(0, 0);
        int rnk = 0;
        if (i < e) {
            rc.x = row[i];
            rc.y = col[i];
            rnk = atomicAdd(&hist[rc.y >> BSH], 1);
        }
        myrc[k] = rc;
        myrank[k] = rnk;
    }
    __syncthreads();

    excl[t] = hist[t];
    __syncthreads();
    for (int off = 1; off < 256; off <<= 1) {
        int mine = excl[t];
        int add  = (t >= off) ? excl[t - off] : 0;
        __syncthreads();
        excl[t] = mine + add;
        __syncthreads();
    }
    excl[t] -= hist[t];
    rbase[t] = (hist[t] > 0) ? atomicAdd(&bcur[t], hist[t]) : 0;
    __syncthreads();

    #pragma unroll
    for (int k = 0; k < 16; k++) {
        int i = wgbase + k * 256 + t;
        if (i < e) stage[excl[myrc[k].y >> BSH] + myrank[k]] = myrc[k];
    }
    __syncthreads();

    for (int j = t; j < total; j += 256) {
        int2 rc = stage[j];
        int b = rc.y >> BSH;
        ebuck[rbase[b] + (j - excl[b])] = rc;
    }
}

// ---------------- per-bucket node histogram + scan -> colptr/cursor/dinv ----------------
__global__ __launch_bounds__(256) void k_nodeptr(const int2* __restrict__ ebuck, const int* __restrict__ bbase,
                                                 int* __restrict__ colptr, int* __restrict__ cursor,
                                                 float* __restrict__ dinv, int n) {
    __shared__ int h[512];
    __shared__ int s[256];
    int b = blockIdx.x;
    int t = threadIdx.x;
    h[t] = 0;
    h[t + 256] = 0;
    __syncthreads();
    int e_lo = bbase[b], e_hi = bbase[b + 1];
    for (int i = e_lo + t; i < e_hi; i += 256) {
        int2 rc = ebuck[i];
        atomicAdd(&h[rc.y & 511], 1);
    }
    __syncthreads();
    int a0 = h[2 * t], a1 = h[2 * t + 1];
    s[t] = a0 + a1;
    __syncthreads();
    for (int off = 1; off < 256; off <<= 1) {
        int mine = s[t];
        int add  = (t >= off) ? s[t - off] : 0;
        __syncthreads();
        s[t] = mine + add;
        __syncthreads();
    }
    int sexcl = s[t] - (a0 + a1);
    int g0 = (b << BSH) + 2 * t;
    int g1 = g0 + 1;
    if (g0 < n) {
        int cp = e_lo + sexcl;
        colptr[g0] = cp;
        cursor[g0] = cp;
        dinv[g0] = rsqrtf((float)(a0 + 1));
    }
    if (g1 < n) {
        int cp = e_lo + sexcl + a0;
        colptr[g1] = cp;
        cursor[g1] = cp;
        dinv[g1] = rsqrtf((float)(a1 + 1));
    }
}

// ---------------- fill esrc from bucketed edges ----------------
__global__ __launch_bounds__(256) void k_fill2(const int2* __restrict__ ebuck, const int* __restrict__ bbase,
                                               int* __restrict__ cursor, int* __restrict__ esrc) {
    int b = blockIdx.x >> 2;
    int sub = blockIdx.x & 3;
    int e_lo = bbase[b], e_hi = bbase[b + 1];
    for (int i = e_lo + sub * 256 + threadIdx.x; i < e_hi; i += 1024) {
        int2 rc = ebuck[i];
        int pos = atomicAdd(&cursor[rc.y], 1);
        esrc[pos] = rc.x;
    }
}

// ---------------- weight conversion: fp32 -> f16 hi/lo in MFMA-frag order ----------------
__global__ __launch_bounds__(256) void k_wconv(const float* __restrict__ w, f16* __restrict__ whi,
                                               f16* __restrict__ wlo) {
    int fi = blockIdx.x * 256 + threadIdx.x;   // 0..16383
    int j  = fi & 7;
    int l  = (fi >> 3) & 63;
    int ks = (fi >> 9) & 3;
    int ct = fi >> 11;
    int k = ks * 32 + (l >> 4) * 8 + j;
    int c = ct * 16 + (l & 15);
    float x = w[k * 128 + c];
    f16 hi = (f16)x;
    f16 lo = (f16)(x - (float)hi);
    whi[fi] = hi;
    wlo[fi] = lo;
}

// ---------------- GEMM (fp32 input, layer 1): A[r] = f16(dinv[r] * (in[r] @ W + b)) ----------------
__global__ __launch_bounds__(256) void k_gemm_f32in(const float* __restrict__ in, const f16* __restrict__ whi,
                                                    const f16* __restrict__ wlo, const float* __restrict__ bias,
                                                    const float* __restrict__ dinv, f16* __restrict__ out, int n) {
    int lane = threadIdx.x & 63;
    int wid  = threadIdx.x >> 6;
    int wr = wid >> 1, wc = wid & 1;
    int rbase = blockIdx.x * 64 + wr * 32;
    int rowA = lane & 15;
    int kg   = lane >> 4;

    f32x4 acc[2][4];
    #pragma unroll
    for (int i = 0; i < 2; i++)
        #pragma unroll
        for (int j = 0; j < 4; j++) acc[i][j] = (f32x4){0.f, 0.f, 0.f, 0.f};

    #pragma unroll
    for (int ks = 0; ks < 4; ks++) {
        f16x8 ah[2], al[2];
        #pragma unroll
        for (int rt = 0; rt < 2; rt++) {
            int r = rbase + rt * 16 + rowA;
            int k0 = ks * 32 + kg * 8;
            float4 x0 = make_float4(0.f, 0.f, 0.f, 0.f), x1 = x0;
            if (r < n) {
                const float4* p = (const float4*)(in + (size_t)r * 128 + k0);
                x0 = p[0];
                x1 = p[1];
            }
            float xs[8] = {x0.x, x0.y, x0.z, x0.w, x1.x, x1.y, x1.z, x1.w};
            #pragma unroll
            for (int j = 0; j < 8; j++) {
                f16 h = (f16)xs[j];
                ah[rt][j] = h;
                al[rt][j] = (f16)(xs[j] - (float)h);
            }
        }
        f16x8 bh[4], bl[4];
        #pragma unroll
        for (int ct = 0; ct < 4; ct++) {
            int g = ((wc * 4 + ct) * 4 + ks);
            size_t idx = (size_t)(g * 64 + lane) * 8;
            bh[ct] = *(const f16x8*)(whi + idx);
            bl[ct] = *(const f16x8*)(wlo + idx);
        }
        #pragma unroll
        for (int rt = 0; rt < 2; rt++)
            #pragma unroll
            for (int ct = 0; ct < 4; ct++) {
                acc[rt][ct] = __builtin_amdgcn_mfma_f32_16x16x32_f16(al[rt], bh[ct], acc[rt][ct], 0, 0, 0);
                acc[rt][ct] = __builtin_amdgcn_mfma_f32_16x16x32_f16(ah[rt], bl[ct], acc[rt][ct], 0, 0, 0);
                acc[rt][ct] = __builtin_amdgcn_mfma_f32_16x16x32_f16(ah[rt], bh[ct], acc[rt][ct], 0, 0, 0);
            }
    }

    int cl = lane & 15;
    int rq = lane >> 4;
    #pragma unroll
    for (int rt = 0; rt < 2; rt++) {
        #pragma unroll
        for (int ct = 0; ct < 4; ct++) {
            int c = wc * 64 + ct * 16 + cl;
            float bv = bias[c];
            #pragma unroll
            for (int reg = 0; reg < 4; reg++) {
                int r = rbase + rt * 16 + rq * 4 + reg;
                if (r < n) {
                    float dv = dinv[r];
                    out[(size_t)r * 128 + c] = (f16)(dv * (acc[rt][ct][reg] + bv));
                }
            }
        }
    }
}

// ---------------- GEMM (fp16 input, layers 2,3) ----------------
__global__ __launch_bounds__(256) void k_gemm_f16in(const f16* __restrict__ in, const f16* __restrict__ whi,
                                                    const f16* __restrict__ wlo, const float* __restrict__ bias,
                                                    const float* __restrict__ dinv, f16* __restrict__ out, int n) {
    int lane = threadIdx.x & 63;
    int wid  = threadIdx.x >> 6;
    int wr = wid >> 1, wc = wid & 1;
    int rbase = blockIdx.x * 64 + wr * 32;
    int rowA = lane & 15;
    int kg   = lane >> 4;

    f32x4 acc[2][4];
    #pragma unroll
    for (int i = 0; i < 2; i++)
        #pragma unroll
        for (int j = 0; j < 4; j++) acc[i][j] = (f32x4){0.f, 0.f, 0.f, 0.f};

    #pragma unroll
    for (int ks = 0; ks < 4; ks++) {
        f16x8 ah[2];
        #pragma unroll
        for (int rt = 0; rt < 2; rt++) {
            int r = rbase + rt * 16 + rowA;
            int k0 = ks * 32 + kg * 8;
            f16x8 v = {};
            if (r < n) v = *(const f16x8*)(in + (size_t)r * 128 + k0);
            ah[rt] = v;
        }
        f16x8 bh[4], bl[4];
        #pragma unroll
        for (int ct = 0; ct < 4; ct++) {
            int g = ((wc * 4 + ct) * 4 + ks);
            size_t idx = (size_t)(g * 64 + lane) * 8;
            bh[ct] = *(const f16x8*)(whi + idx);
            bl[ct] = *(const f16x8*)(wlo + idx);
        }
        #pragma unroll
        for (int rt = 0; rt < 2; rt++)
            #pragma unroll
            for (int ct = 0; ct < 4; ct++) {
                acc[rt][ct] = __builtin_amdgcn_mfma_f32_16x16x32_f16(ah[rt], bl[ct], acc[rt][ct], 0, 0, 0);
                acc[rt][ct] = __builtin_amdgcn_mfma_f32_16x16x32_f16(ah[rt], bh[ct], acc[rt][ct], 0, 0, 0);
            }
    }

    int cl = lane & 15;
    int rq = lane >> 4;
    #pragma unroll
    for (int rt = 0; rt < 2; rt++) {
        #pragma unroll
        for (int ct = 0; ct < 4; ct++) {
            int c = wc * 64 + ct * 16 + cl;
            float bv = bias[c];
            #pragma unroll
            for (int reg = 0; reg < 4; reg++) {
                int r = rbase + rt * 16 + rq * 4 + reg;
                if (r < n) {
                    float dv = dinv[r];
                    out[(size_t)r * 128 + c] = (f16)(dv * (acc[rt][ct][reg] + bv));
                }
            }
        }
    }
}

// ---------------- Aggregation v3: 4 edges per wave-load ----------------
__global__ __launch_bounds__(256) void k_agg(const f16* __restrict__ A, const int* __restrict__ colptr,
                                             const int* __restrict__ esrc, const float* __restrict__ dinv,
                                             f16* __restrict__ B, int n) {
    int lane = threadIdx.x & 63;
    int v = blockIdx.x * 4 + (threadIdx.x >> 6);
    if (v >= n) return;
    int eg = lane >> 4;
    int cs = lane & 15;
    const f16x8* __restrict__ A8 = (const f16x8*)A;
    int p0 = colptr[v], p1 = colptr[v + 1];
    int total = p1 - p0 + 1;   // neighbors + self

    float acc[8];
    #pragma unroll
    for (int j = 0; j < 8; j++) acc[j] = 0.f;

    for (int base = 0; base < total; base += 8) {
        int q0 = base + eg;
        int q1 = base + 4 + eg;
        bool ok0 = q0 < total, ok1 = q1 < total;
        int s0 = (q0 < total - 1) ? esrc[p0 + q0] : v;
        int s1 = (q1 < total - 1) ? esrc[p0 + q1] : v;
        f16x8 r0 = A8[(size_t)s0 * 16 + cs];
        f16x8 r1 = A8[(size_t)s1 * 16 + cs];
        float m0 = ok0 ? 1.f : 0.f;
        float m1 = ok1 ? 1.f : 0.f;
        #pragma unroll
        for (int j = 0; j < 8; j++) acc[j] = fmaf(m0, (float)r0[j], acc[j]);
        #pragma unroll
        for (int j = 0; j < 8; j++) acc[j] = fmaf(m1, (float)r1[j], acc[j]);
    }

    #pragma unroll
    for (int j = 0; j < 8; j++) {
        acc[j] += __shfl_xor(acc[j], 32, 64);
        acc[j] += __shfl_xor(acc[j], 16, 64);
    }

    if (lane < 16) {
        float d = dinv[v];
        f16x8 o;
        #pragma unroll
        for (int j = 0; j < 8; j++) o[j] = (f16)fmaxf(d * acc[j], 0.f);
        ((f16x8*)B)[(size_t)v * 16 + cs] = o;
    }
}

// ---------------- Pooling (batch is sorted), B fp16 ----------------
__global__ __launch_bounds__(128) void k_pool(const f16* __restrict__ B, const int* __restrict__ batch,
                                              float* __restrict__ gsum, int* __restrict__ gcnt, int n) {
    int c = threadIdx.x;
    int base = blockIdx.x * 64;
    if (base >= n) return;
    int end = min(base + 64, n);
    int curg = batch[base];
    float acc = 0.f;
    int cnt = 0;
    for (int i = base; i < end; i++) {
        int g = batch[i];
        if (g != curg) {
            atomicAdd(&gsum[curg * 128 + c], acc);
            if (c == 0) atomicAdd(&gcnt[curg], cnt);
            acc = 0.f; cnt = 0; curg = g;
        }
        acc += (float)B[(size_t)i * 128 + c];
        cnt++;
    }
    atomicAdd(&gsum[curg * 128 + c], acc);
    if (c == 0) atomicAdd(&gcnt[curg], cnt);
}

// ---------------- Head ----------------
__global__ __launch_bounds__(128) void k_head(const float* __restrict__ gsum, const int* __restrict__ gcnt,
                                              const float* __restrict__ hw1, const float* __restrict__ hb1,
                                              const float* __restrict__ hw2, const float* __restrict__ hb2,
                                              float* __restrict__ out) {
    __shared__ float mean[128];
    __shared__ float red[128];
    int g = blockIdx.x;
    int c = threadIdx.x;
    float cntf = fmaxf((float)gcnt[g], 1.0f);
    mean[c] = gsum[g * 128 + c] / cntf;
    __syncthreads();
    float h = hb1[c];
    for (int k = 0; k < 128; k++) h = fmaf(mean[k], hw1[k * 128 + c], h);
    h = fmaxf(h, 0.f);
    red[c] = h * hw2[c];
    __syncthreads();
    for (int s = 64; s > 0; s >>= 1) {
        if (c < s) red[c] += red[c + s];
        __syncthreads();
    }
    if (c == 0) out[g] = red[0] + hb2[0];
}

// ---------------- launch ----------------
extern "C" void kernel_launch(void* const* d_in, const int* in_sizes, int n_in,
                              void* d_out, int out_size, void* d_ws, size_t ws_size,
                              hipStream_t stream) {
    const float* x   = (const float*)d_in[0];
    const int*  edge = (const int*)d_in[1];
    const int*  batch= (const int*)d_in[2];
    const float* w1  = (const float*)d_in[3];
    const float* b1  = (const float*)d_in[4];
    const float* w2  = (const float*)d_in[5];
    const float* b2  = (const float*)d_in[6];
    const float* w3  = (const float*)d_in[7];
    const float* b3  = (const float*)d_in[8];
    const float* hw1 = (const float*)d_in[9];
    const float* hb1 = (const float*)d_in[10];
    const float* hw2 = (const float*)d_in[11];
    const float* hb2 = (const float*)d_in[12];
    float* out = (float*)d_out;

    const int n = in_sizes[0] / 128;
    const int e = in_sizes[1] / 2;
    const int* row = edge;
    const int* col = edge + e;

    char* wsb = (char*)d_ws;
    size_t off = 0;
    auto alloc = [&](size_t bytes) -> void* {
        void* p = wsb + off;
        off = (off + bytes + 511) & ~size_t(511);
        return p;
    };
    f16*   A      = (f16*)  alloc((size_t)n * 128 * 2);   // fp16 activations (gemm out)
    f16*   Bb     = (f16*)  alloc((size_t)n * 128 * 2);   // fp16 activations (agg out)
    int2*  ebuck  = (int2*) alloc((size_t)e * 8);         // bucketed edges
    float* dinv   = (float*)alloc((size_t)n * 4);
    int*   colptr = (int*)  alloc((size_t)(n + 1) * 4);
    int*   cursor = (int*)  alloc((size_t)n * 4);
    int*   bcnt   = (int*)  alloc(1024);
    int*   bbase  = (int*)  alloc(1028 + 508);  // 257 ints (padded)
    int*   bcur   = (int*)  alloc(1024);
    int*   esrc   = (int*)  alloc((size_t)e * 4);
    float* gsum   = (float*)alloc(64 * 128 * 4);
    int*   gcnt   = (int*)  alloc(64 * 4);
    f16*   whi    = (f16*)  alloc(3 * 16384 * 2);
    f16*   wlo    = (f16*)  alloc(3 * 16384 * 2);

    hipMemsetAsync(bcnt, 0, 1024, stream);
    hipMemsetAsync(gsum, 0, 64 * 128 * 4, stream);
    hipMemsetAsync(gcnt, 0, 64 * 4, stream);

    k_wconv<<<64, 256, 0, stream>>>(w1, whi,             wlo);
    k_wconv<<<64, 256, 0, stream>>>(w2, whi + 16384,     wlo + 16384);
    k_wconv<<<64, 256, 0, stream>>>(w3, whi + 2 * 16384, wlo + 2 * 16384);

    int nwg_e = (e + 4095) / 4096;
    int nbk = (n + (1 << BSH) - 1) >> BSH;
    k_bcount<<<nwg_e, 256, 0, stream>>>(col, bcnt, e);
    k_bscan<<<1, 256, 0, stream>>>(bcnt, bbase, bcur, colptr, e, n);
    k_part<<<nwg_e, 256, 0, stream>>>(row, col, bcur, ebuck, e);
    k_nodeptr<<<nbk, 256, 0, stream>>>(ebuck, bbase, colptr, cursor, dinv, n);
    k_fill2<<<nbk * 4, 256, 0, stream>>>(ebuck, bbase, cursor, esrc);

    int gb = (n + 63) / 64;
    k_gemm_f32in<<<gb, 256, 0, stream>>>(x,  whi,             wlo,             b1, dinv, A, n);
    k_agg <<<(n + 3) / 4, 256, 0, stream>>>(A, colptr, esrc, dinv, Bb, n);
    k_gemm_f16in<<<gb, 256, 0, stream>>>(Bb, whi + 16384,     wlo + 16384,     b2, dinv, A, n);
    k_agg <<<(n + 3) / 4, 256, 0, stream>>>(A, colptr, esrc, dinv, Bb, n);
    k_gemm_f16in<<<gb, 256, 0, stream>>>(Bb, whi + 2 * 16384, wlo + 2 * 16384, b3, dinv, A, n);
    k_agg <<<(n + 3) / 4, 256, 0, stream>>>(A, colptr, esrc, dinv, Bb, n);

    k_pool<<<(n + 63) / 64, 128, 0, stream>>>(Bb, batch, gsum, gcnt, n);
    k_head<<<64, 128, 0, stream>>>(gsum, gcnt, hw1, hb1, hw2, hb2, out);
}